// Round 1
// baseline (1213.499 us; speedup 1.0000x reference)
//
#include <hip/hip_runtime.h>

#define N_NODES 100000
#define N_EDGES 600000
#define NF 128
#define NG 256

// ---------------- preprocessing: degrees, dinv, CSR ----------------

__global__ void k_count(const int* __restrict__ ei, int* __restrict__ counts) {
    int e = blockIdx.x * 256 + threadIdx.x;
    if (e < N_EDGES) atomicAdd(&counts[ei[N_EDGES + e]], 1);
}

__global__ void k_dinv(const int* __restrict__ counts, float* __restrict__ dinv) {
    int i = blockIdx.x * 256 + threadIdx.x;
    if (i < N_NODES) {
        float deg = (float)(counts[i] + 1);  // +1 self-loop; always > 0
        dinv[i] = 1.0f / sqrtf(deg);         // precise (match np ref closely)
    }
}

__global__ void k_scan1(const int* __restrict__ counts, int* __restrict__ row_ptr,
                        int* __restrict__ bsums) {
    __shared__ int s[256];
    int b = blockIdx.x, t = threadIdx.x;
    int base = b * 2048 + t * 8;
    int local[8];
    int sum = 0;
#pragma unroll
    for (int q = 0; q < 8; q++) {
        int idx = base + q;
        int v = (idx < N_NODES) ? counts[idx] : 0;
        local[q] = sum;
        sum += v;
    }
    s[t] = sum;
    __syncthreads();
    for (int off = 1; off < 256; off <<= 1) {
        int v = 0;
        if (t >= off) v = s[t - off];
        __syncthreads();
        s[t] += v;
        __syncthreads();
    }
    int excl = s[t] - sum;  // exclusive prefix of this thread's chunk
#pragma unroll
    for (int q = 0; q < 8; q++) {
        int idx = base + q;
        if (idx < N_NODES) row_ptr[idx] = excl + local[q];
    }
    if (t == 255) bsums[b] = s[255];
}

__global__ void k_scan2(int* bsums, int nb) {
    if (threadIdx.x == 0 && blockIdx.x == 0) {
        int run = 0;
        for (int b = 0; b < nb; b++) { int v = bsums[b]; bsums[b] = run; run += v; }
    }
}

__global__ void k_scan3(int* __restrict__ row_ptr, const int* __restrict__ bsums,
                        int* __restrict__ cursor) {
    int i = blockIdx.x * 256 + threadIdx.x;
    if (i < N_NODES) {
        int v = row_ptr[i] + bsums[i >> 11];
        row_ptr[i] = v;
        cursor[i] = v;
        if (i == 0) row_ptr[N_NODES] = N_EDGES;
    }
}

__global__ void k_fill(const int* __restrict__ ei, int* __restrict__ cursor,
                       int* __restrict__ col) {
    int e = blockIdx.x * 256 + threadIdx.x;
    if (e < N_EDGES) {
        int d = ei[N_EDGES + e];
        int p = atomicAdd(&cursor[d], 1);
        col[p] = ei[e];
    }
}

// ---------------- GEMM: C[M,128] = act(A[M,128]) @ W[128,128] ----------------
// 64 rows/block in LDS (stride 132 -> 2-way bank aliasing only, free).
// 256 threads as 16x16; each thread computes 4 rows x 8 cols.

template <int RELU>
__global__ __launch_bounds__(256) void k_gemm(const float* __restrict__ A,
                                              const float* __restrict__ W,
                                              float* __restrict__ C, int M) {
    __shared__ __align__(16) float As[64 * 132];
    const int t = threadIdx.x;
    const int row0 = blockIdx.x * 64;

#pragma unroll
    for (int q = 0; q < 8; q++) {
        int lin = t + q * 256;          // 0..2047 float4 slots
        int r = lin >> 5, c4 = lin & 31;
        int grow = row0 + r;
        float4 v = make_float4(0.f, 0.f, 0.f, 0.f);
        if (grow < M) v = ((const float4*)(A + (long long)grow * NF))[c4];
        if (RELU) {
            v.x = fmaxf(v.x, 0.f); v.y = fmaxf(v.y, 0.f);
            v.z = fmaxf(v.z, 0.f); v.w = fmaxf(v.w, 0.f);
        }
        *(float4*)&As[r * 132 + c4 * 4] = v;
    }
    __syncthreads();

    const int tx = t & 15, ty = t >> 4;
    const int c0 = tx * 8;
    float acc[4][8];
#pragma unroll
    for (int j = 0; j < 4; j++)
#pragma unroll
        for (int c = 0; c < 8; c++) acc[j][c] = 0.f;

#pragma unroll 4
    for (int k = 0; k < NF; k++) {
        const float* wr = W + k * NF + c0;
        float4 w0 = *(const float4*)wr;
        float4 w1 = *(const float4*)(wr + 4);
        float wv[8] = {w0.x, w0.y, w0.z, w0.w, w1.x, w1.y, w1.z, w1.w};
#pragma unroll
        for (int j = 0; j < 4; j++) {
            float a = As[(ty * 4 + j) * 132 + k];
#pragma unroll
            for (int c = 0; c < 8; c++) acc[j][c] += a * wv[c];
        }
    }

#pragma unroll
    for (int j = 0; j < 4; j++) {
        int grow = row0 + ty * 4 + j;
        if (grow < M) {
            float4 o0 = {acc[j][0], acc[j][1], acc[j][2], acc[j][3]};
            float4 o1 = {acc[j][4], acc[j][5], acc[j][6], acc[j][7]};
            *(float4*)(C + (long long)grow * NF + c0) = o0;
            *(float4*)(C + (long long)grow * NF + c0 + 4) = o1;
        }
    }
}

// ---------------- aggregation: out[i] = b + dinv[i]^2*hw[i] + sum_e dinv[s]*dinv[i]*hw[s]
// one block (128 threads) per dst node; coalesced 512B row gathers.

__global__ void k_agg(const float* __restrict__ hw, const float* __restrict__ dinv,
                      const int* __restrict__ row_ptr, const int* __restrict__ col,
                      const float* __restrict__ bias, float* __restrict__ out) {
    int i = blockIdx.x;
    int f = threadIdx.x;
    float di = dinv[i];
    float acc = bias[f] + hw[(long long)i * NF + f] * di * di;
    int beg = row_ptr[i], end = row_ptr[i + 1];
    for (int e = beg; e < end; e++) {
        int s = col[e];
        float w = dinv[s] * di;
        acc += hw[(long long)s * NF + f] * w;
    }
    out[(long long)i * NF + f] = acc;
}

// ---------------- mean pool per graph (batch is sorted) ----------------

__global__ void k_pool(const float* __restrict__ h, const int* __restrict__ batch,
                       float* __restrict__ pooled) {
    int g = blockIdx.x, f = threadIdx.x;
    int lo = 0, hi = N_NODES;
    while (lo < hi) { int mid = (lo + hi) >> 1; if (batch[mid] < g) lo = mid + 1; else hi = mid; }
    int start = lo;
    hi = N_NODES;
    while (lo < hi) { int mid = (lo + hi) >> 1; if (batch[mid] < g + 1) lo = mid + 1; else hi = mid; }
    int end = lo;
    float acc = 0.f;
    for (int n = start; n < end; n++) acc += fmaxf(h[(long long)n * NF + f], 0.f);
    float cnt = (float)(end - start);
    pooled[g * NF + f] = acc / fmaxf(cnt, 1.f);
}

// ---------------- summary MLP: relu(pooled@Ws1+bs1)@Ws2+bs2 ----------------

__global__ void k_mlp(const float* __restrict__ pooled, const float* __restrict__ Ws1,
                      const float* __restrict__ bs1, const float* __restrict__ Ws2,
                      const float* __restrict__ bs2, float* __restrict__ out) {
    __shared__ float row[NF];
    __shared__ float red[NF];
    int g = blockIdx.x, f = threadIdx.x;
    row[f] = pooled[g * NF + f];
    __syncthreads();
    float t = bs1[f];
    for (int k = 0; k < NF; k++) t += row[k] * Ws1[k * NF + f];
    t = fmaxf(t, 0.f);
    red[f] = t * Ws2[f];
    __syncthreads();
    for (int s = 64; s > 0; s >>= 1) {
        if (f < s) red[f] += red[f + s];
        __syncthreads();
    }
    if (f == 0) out[g] = red[0] + bs2[0];
}

// ---------------- driver ----------------

extern "C" void kernel_launch(void* const* d_in, const int* in_sizes, int n_in,
                              void* d_out, int out_size, void* d_ws, size_t ws_size,
                              hipStream_t stream) {
    const float* x    = (const float*)d_in[0];
    const int*   ei   = (const int*)d_in[1];
    const int*   batch= (const int*)d_in[2];
    const float* W1 = (const float*)d_in[3];  const float* b1 = (const float*)d_in[4];
    const float* W2 = (const float*)d_in[5];  const float* b2 = (const float*)d_in[6];
    const float* W3 = (const float*)d_in[7];  const float* b3 = (const float*)d_in[8];
    const float* W4 = (const float*)d_in[9];  const float* b4 = (const float*)d_in[10];
    const float* Ws1= (const float*)d_in[11]; const float* bs1= (const float*)d_in[12];
    const float* Ws2= (const float*)d_in[13]; const float* bs2= (const float*)d_in[14];
    float* out = (float*)d_out;

    char* ws = (char*)d_ws;
    size_t off = 0;
    auto alloc = [&](size_t bytes) {
        void* p = ws + off;
        off += (bytes + 255) & ~(size_t)255;
        return p;
    };
    float* bufA   = (float*)alloc((size_t)N_NODES * NF * 4);
    float* bufB   = (float*)alloc((size_t)N_NODES * NF * 4);
    int*   counts = (int*)alloc((size_t)N_NODES * 4);
    int*   row_ptr= (int*)alloc((size_t)(N_NODES + 1) * 4);
    int*   cursor = (int*)alloc((size_t)N_NODES * 4);
    int*   col    = (int*)alloc((size_t)N_EDGES * 4);
    int*   bsums  = (int*)alloc(64 * 4);
    float* dinv   = (float*)alloc((size_t)N_NODES * 4);
    float* pooled = (float*)alloc((size_t)NG * NF * 4);

    hipMemsetAsync(counts, 0, (size_t)N_NODES * 4, stream);
    k_count<<<(N_EDGES + 255) / 256, 256, 0, stream>>>(ei, counts);
    k_dinv<<<(N_NODES + 255) / 256, 256, 0, stream>>>(counts, dinv);
    int nscan = (N_NODES + 2047) / 2048;  // 49
    k_scan1<<<nscan, 256, 0, stream>>>(counts, row_ptr, bsums);
    k_scan2<<<1, 64, 0, stream>>>(bsums, nscan);
    k_scan3<<<(N_NODES + 255) / 256, 256, 0, stream>>>(row_ptr, bsums, cursor);
    k_fill<<<(N_EDGES + 255) / 256, 256, 0, stream>>>(ei, cursor, col);

    int gblocks = (N_NODES + 63) / 64;
    // layer 1 (input x, no relu on load)
    k_gemm<0><<<gblocks, 256, 0, stream>>>(x, W1, bufB, N_NODES);
    k_agg<<<N_NODES, NF, 0, stream>>>(bufB, dinv, row_ptr, col, b1, bufA);
    // layers 2-4 (relu fused into gemm load)
    k_gemm<1><<<gblocks, 256, 0, stream>>>(bufA, W2, bufB, N_NODES);
    k_agg<<<N_NODES, NF, 0, stream>>>(bufB, dinv, row_ptr, col, b2, bufA);
    k_gemm<1><<<gblocks, 256, 0, stream>>>(bufA, W3, bufB, N_NODES);
    k_agg<<<N_NODES, NF, 0, stream>>>(bufB, dinv, row_ptr, col, b3, bufA);
    k_gemm<1><<<gblocks, 256, 0, stream>>>(bufA, W4, bufB, N_NODES);
    k_agg<<<N_NODES, NF, 0, stream>>>(bufB, dinv, row_ptr, col, b4, bufA);
    // relu fused into pool load
    k_pool<<<NG, NF, 0, stream>>>(bufA, batch, pooled);
    k_mlp<<<NG, NF, 0, stream>>>(pooled, Ws1, bs1, Ws2, bs2, out);
}

// Round 2
// 799.997 us; speedup vs baseline: 1.5169x; 1.5169x over previous
//
#include <hip/hip_runtime.h>

#define N_NODES 100000
#define N_EDGES 600000
#define NF 128
#define NG 256

// ---------------- preprocessing: degrees, dinv, CSR ----------------

__global__ void k_count(const int* __restrict__ ei, int* __restrict__ counts) {
    int e = blockIdx.x * 256 + threadIdx.x;
    if (e < N_EDGES) atomicAdd(&counts[ei[N_EDGES + e]], 1);
}

__global__ void k_dinv(const int* __restrict__ counts, float* __restrict__ dinv) {
    int i = blockIdx.x * 256 + threadIdx.x;
    if (i < N_NODES) {
        float deg = (float)(counts[i] + 1);  // +1 self-loop; always > 0
        dinv[i] = 1.0f / sqrtf(deg);
    }
}

__global__ void k_scan1(const int* __restrict__ counts, int* __restrict__ row_ptr,
                        int* __restrict__ bsums) {
    __shared__ int s[256];
    int b = blockIdx.x, t = threadIdx.x;
    int base = b * 2048 + t * 8;
    int local[8];
    int sum = 0;
#pragma unroll
    for (int q = 0; q < 8; q++) {
        int idx = base + q;
        int v = (idx < N_NODES) ? counts[idx] : 0;
        local[q] = sum;
        sum += v;
    }
    s[t] = sum;
    __syncthreads();
    for (int off = 1; off < 256; off <<= 1) {
        int v = 0;
        if (t >= off) v = s[t - off];
        __syncthreads();
        s[t] += v;
        __syncthreads();
    }
    int excl = s[t] - sum;
#pragma unroll
    for (int q = 0; q < 8; q++) {
        int idx = base + q;
        if (idx < N_NODES) row_ptr[idx] = excl + local[q];
    }
    if (t == 255) bsums[b] = s[255];
}

__global__ void k_scan2(int* bsums, int nb) {
    if (threadIdx.x == 0 && blockIdx.x == 0) {
        int run = 0;
        for (int b = 0; b < nb; b++) { int v = bsums[b]; bsums[b] = run; run += v; }
    }
}

__global__ void k_scan3(int* __restrict__ row_ptr, const int* __restrict__ bsums,
                        int* __restrict__ cursor) {
    int i = blockIdx.x * 256 + threadIdx.x;
    if (i < N_NODES) {
        int v = row_ptr[i] + bsums[i >> 11];
        row_ptr[i] = v;
        cursor[i] = v;
        if (i == 0) row_ptr[N_NODES] = N_EDGES;
    }
}

__global__ void k_fill(const int* __restrict__ ei, int* __restrict__ cursor,
                       int* __restrict__ col) {
    int e = blockIdx.x * 256 + threadIdx.x;
    if (e < N_EDGES) {
        int d = ei[N_EDGES + e];
        int p = atomicAdd(&cursor[d], 1);
        col[p] = ei[e];
    }
}

// ---------------- GEMM: C[M,128] = act(A[M,128]) @ W[128,128] ----------------

template <int RELU>
__global__ __launch_bounds__(256) void k_gemm(const float* __restrict__ A,
                                              const float* __restrict__ W,
                                              float* __restrict__ C, int M) {
    __shared__ __align__(16) float As[64 * 132];
    const int t = threadIdx.x;
    const int row0 = blockIdx.x * 64;

#pragma unroll
    for (int q = 0; q < 8; q++) {
        int lin = t + q * 256;
        int r = lin >> 5, c4 = lin & 31;
        int grow = row0 + r;
        float4 v = make_float4(0.f, 0.f, 0.f, 0.f);
        if (grow < M) v = ((const float4*)(A + (long long)grow * NF))[c4];
        if (RELU) {
            v.x = fmaxf(v.x, 0.f); v.y = fmaxf(v.y, 0.f);
            v.z = fmaxf(v.z, 0.f); v.w = fmaxf(v.w, 0.f);
        }
        *(float4*)&As[r * 132 + c4 * 4] = v;
    }
    __syncthreads();

    const int tx = t & 15, ty = t >> 4;
    const int c0 = tx * 8;
    float acc[4][8];
#pragma unroll
    for (int j = 0; j < 4; j++)
#pragma unroll
        for (int c = 0; c < 8; c++) acc[j][c] = 0.f;

#pragma unroll 4
    for (int k = 0; k < NF; k++) {
        const float* wr = W + k * NF + c0;
        float4 w0 = *(const float4*)wr;
        float4 w1 = *(const float4*)(wr + 4);
        float wv[8] = {w0.x, w0.y, w0.z, w0.w, w1.x, w1.y, w1.z, w1.w};
#pragma unroll
        for (int j = 0; j < 4; j++) {
            float a = As[(ty * 4 + j) * 132 + k];
#pragma unroll
            for (int c = 0; c < 8; c++) acc[j][c] += a * wv[c];
        }
    }

#pragma unroll
    for (int j = 0; j < 4; j++) {
        int grow = row0 + ty * 4 + j;
        if (grow < M) {
            float4 o0 = {acc[j][0], acc[j][1], acc[j][2], acc[j][3]};
            float4 o1 = {acc[j][4], acc[j][5], acc[j][6], acc[j][7]};
            *(float4*)(C + (long long)grow * NF + c0) = o0;
            *(float4*)(C + (long long)grow * NF + c0 + 4) = o1;
        }
    }
}

// ---------------- aggregation ----------------

__global__ void k_agg(const float* __restrict__ hw, const float* __restrict__ dinv,
                      const int* __restrict__ row_ptr, const int* __restrict__ col,
                      const float* __restrict__ bias, float* __restrict__ out) {
    int i = blockIdx.x;
    int f = threadIdx.x;
    float di = dinv[i];
    float acc = bias[f] + hw[(long long)i * NF + f] * di * di;
    int beg = row_ptr[i], end = row_ptr[i + 1];
    for (int e = beg; e < end; e++) {
        int s = col[e];
        float w = dinv[s] * di;
        acc += hw[(long long)s * NF + f] * w;
    }
    out[(long long)i * NF + f] = acc;
}

// ---------------- node-parallel mean pool (sums; divide in k_mlp) ----------------
// 64 nodes per block, 128 threads (one per feature). Batch is sorted, so each
// block touches 1-2 graphs: accumulate in register, atomic-flush on boundary.

#define POOL_CHUNK 64

__global__ __launch_bounds__(128) void k_pool2(const float* __restrict__ h,
                                               const int* __restrict__ batch,
                                               float* __restrict__ pooled) {
    int f = threadIdx.x;
    int n0 = blockIdx.x * POOL_CHUNK;
    int n1 = n0 + POOL_CHUNK;
    if (n1 > N_NODES) n1 = N_NODES;
    if (n0 >= N_NODES) return;
    int g = batch[n0];
    float acc = 0.f;
    for (int n = n0; n < n1; n++) {
        int gn = batch[n];
        if (gn != g) {
            atomicAdd(&pooled[g * NF + f], acc);
            acc = 0.f;
            g = gn;
        }
        acc += fmaxf(h[(long long)n * NF + f], 0.f);
    }
    atomicAdd(&pooled[g * NF + f], acc);
}

// ---------------- summary MLP: relu((pooled/cnt)@Ws1+bs1)@Ws2+bs2 ----------------

__global__ void k_mlp(const float* __restrict__ pooled, const int* __restrict__ batch,
                      const float* __restrict__ Ws1, const float* __restrict__ bs1,
                      const float* __restrict__ Ws2, const float* __restrict__ bs2,
                      float* __restrict__ out) {
    __shared__ float row[NF];
    __shared__ float red[NF];
    int g = blockIdx.x, f = threadIdx.x;
    // count nodes in graph g by binary search (batch sorted)
    int lo = 0, hi = N_NODES;
    while (lo < hi) { int mid = (lo + hi) >> 1; if (batch[mid] < g) lo = mid + 1; else hi = mid; }
    int start = lo;
    hi = N_NODES;
    while (lo < hi) { int mid = (lo + hi) >> 1; if (batch[mid] < g + 1) lo = mid + 1; else hi = mid; }
    float cnt = (float)(lo - start);
    row[f] = pooled[g * NF + f] / fmaxf(cnt, 1.f);
    __syncthreads();
    float t = bs1[f];
    for (int k = 0; k < NF; k++) t += row[k] * Ws1[k * NF + f];
    t = fmaxf(t, 0.f);
    red[f] = t * Ws2[f];
    __syncthreads();
    for (int s = 64; s > 0; s >>= 1) {
        if (f < s) red[f] += red[f + s];
        __syncthreads();
    }
    if (f == 0) out[g] = red[0] + bs2[0];
}

// ---------------- driver ----------------

extern "C" void kernel_launch(void* const* d_in, const int* in_sizes, int n_in,
                              void* d_out, int out_size, void* d_ws, size_t ws_size,
                              hipStream_t stream) {
    const float* x    = (const float*)d_in[0];
    const int*   ei   = (const int*)d_in[1];
    const int*   batch= (const int*)d_in[2];
    const float* W1 = (const float*)d_in[3];  const float* b1 = (const float*)d_in[4];
    const float* W2 = (const float*)d_in[5];  const float* b2 = (const float*)d_in[6];
    const float* W3 = (const float*)d_in[7];  const float* b3 = (const float*)d_in[8];
    const float* W4 = (const float*)d_in[9];  const float* b4 = (const float*)d_in[10];
    const float* Ws1= (const float*)d_in[11]; const float* bs1= (const float*)d_in[12];
    const float* Ws2= (const float*)d_in[13]; const float* bs2= (const float*)d_in[14];
    float* out = (float*)d_out;

    char* ws = (char*)d_ws;
    size_t off = 0;
    auto alloc = [&](size_t bytes) {
        void* p = ws + off;
        off += (bytes + 255) & ~(size_t)255;
        return p;
    };
    float* bufA   = (float*)alloc((size_t)N_NODES * NF * 4);
    float* bufB   = (float*)alloc((size_t)N_NODES * NF * 4);
    int*   counts = (int*)alloc((size_t)N_NODES * 4);
    int*   row_ptr= (int*)alloc((size_t)(N_NODES + 1) * 4);
    int*   cursor = (int*)alloc((size_t)N_NODES * 4);
    int*   col    = (int*)alloc((size_t)N_EDGES * 4);
    int*   bsums  = (int*)alloc(64 * 4);
    float* dinv   = (float*)alloc((size_t)N_NODES * 4);
    float* pooled = (float*)alloc((size_t)NG * NF * 4);

    hipMemsetAsync(counts, 0, (size_t)N_NODES * 4, stream);
    hipMemsetAsync(pooled, 0, (size_t)NG * NF * 4, stream);
    k_count<<<(N_EDGES + 255) / 256, 256, 0, stream>>>(ei, counts);
    k_dinv<<<(N_NODES + 255) / 256, 256, 0, stream>>>(counts, dinv);
    int nscan = (N_NODES + 2047) / 2048;  // 49
    k_scan1<<<nscan, 256, 0, stream>>>(counts, row_ptr, bsums);
    k_scan2<<<1, 64, 0, stream>>>(bsums, nscan);
    k_scan3<<<(N_NODES + 255) / 256, 256, 0, stream>>>(row_ptr, bsums, cursor);
    k_fill<<<(N_EDGES + 255) / 256, 256, 0, stream>>>(ei, cursor, col);

    int gblocks = (N_NODES + 63) / 64;
    k_gemm<0><<<gblocks, 256, 0, stream>>>(x, W1, bufB, N_NODES);
    k_agg<<<N_NODES, NF, 0, stream>>>(bufB, dinv, row_ptr, col, b1, bufA);
    k_gemm<1><<<gblocks, 256, 0, stream>>>(bufA, W2, bufB, N_NODES);
    k_agg<<<N_NODES, NF, 0, stream>>>(bufB, dinv, row_ptr, col, b2, bufA);
    k_gemm<1><<<gblocks, 256, 0, stream>>>(bufA, W3, bufB, N_NODES);
    k_agg<<<N_NODES, NF, 0, stream>>>(bufB, dinv, row_ptr, col, b3, bufA);
    k_gemm<1><<<gblocks, 256, 0, stream>>>(bufA, W4, bufB, N_NODES);
    k_agg<<<N_NODES, NF, 0, stream>>>(bufB, dinv, row_ptr, col, b4, bufA);

    int pblocks = (N_NODES + POOL_CHUNK - 1) / POOL_CHUNK;
    k_pool2<<<pblocks, 128, 0, stream>>>(bufA, batch, pooled);
    k_mlp<<<NG, 128, 0, stream>>>(pooled, batch, Ws1, bs1, Ws2, bs2, out);
}

// Round 3
// 772.152 us; speedup vs baseline: 1.5716x; 1.0361x over previous
//
#include <hip/hip_runtime.h>

#define N_NODES 100000
#define N_EDGES 600000
#define NF 128
#define NG 256

// ---------------- preprocessing: degrees, dinv, CSR ----------------

__global__ void k_count(const int* __restrict__ ei, int* __restrict__ counts) {
    int e = blockIdx.x * 256 + threadIdx.x;
    if (e < N_EDGES) atomicAdd(&counts[ei[N_EDGES + e]], 1);
}

__global__ void k_dinv(const int* __restrict__ counts, float* __restrict__ dinv) {
    int i = blockIdx.x * 256 + threadIdx.x;
    if (i < N_NODES) {
        float deg = (float)(counts[i] + 1);  // +1 self-loop; always > 0
        dinv[i] = 1.0f / sqrtf(deg);
    }
}

__global__ void k_scan1(const int* __restrict__ counts, int* __restrict__ row_ptr,
                        int* __restrict__ bsums) {
    __shared__ int s[256];
    int b = blockIdx.x, t = threadIdx.x;
    int base = b * 2048 + t * 8;
    int local[8];
    int sum = 0;
#pragma unroll
    for (int q = 0; q < 8; q++) {
        int idx = base + q;
        int v = (idx < N_NODES) ? counts[idx] : 0;
        local[q] = sum;
        sum += v;
    }
    s[t] = sum;
    __syncthreads();
    for (int off = 1; off < 256; off <<= 1) {
        int v = 0;
        if (t >= off) v = s[t - off];
        __syncthreads();
        s[t] += v;
        __syncthreads();
    }
    int excl = s[t] - sum;
#pragma unroll
    for (int q = 0; q < 8; q++) {
        int idx = base + q;
        if (idx < N_NODES) row_ptr[idx] = excl + local[q];
    }
    if (t == 255) bsums[b] = s[255];
}

__global__ void k_scan2(int* bsums, int nb) {
    if (threadIdx.x == 0 && blockIdx.x == 0) {
        int run = 0;
        for (int b = 0; b < nb; b++) { int v = bsums[b]; bsums[b] = run; run += v; }
    }
}

__global__ void k_scan3(int* __restrict__ row_ptr, const int* __restrict__ bsums,
                        int* __restrict__ cursor) {
    int i = blockIdx.x * 256 + threadIdx.x;
    if (i < N_NODES) {
        int v = row_ptr[i] + bsums[i >> 11];
        row_ptr[i] = v;
        cursor[i] = v;
        if (i == 0) row_ptr[N_NODES] = N_EDGES;
    }
}

__global__ void k_fill(const int* __restrict__ ei, int* __restrict__ cursor,
                       int* __restrict__ col) {
    int e = blockIdx.x * 256 + threadIdx.x;
    if (e < N_EDGES) {
        int d = ei[N_EDGES + e];
        int p = atomicAdd(&cursor[d], 1);
        col[p] = ei[e];
    }
}

// ---------------- GEMM: C[M,128] = act(A[M,128]) @ W[128,128] ----------------
// A tile transposed in LDS: AsT[k][64 rows] (32 KB). Inner loop per k:
// 1x ds_read_b128 (4 rows) + 2x global b128 (W, L1/L2-resident) + 32 FMA.

template <int RELU>
__global__ __launch_bounds__(256) void k_gemm(const float* __restrict__ A,
                                              const float* __restrict__ W,
                                              float* __restrict__ C, int M) {
    __shared__ __align__(16) float AsT[128 * 64];  // [k][row]
    const int t = threadIdx.x;
    const int row0 = blockIdx.x * 64;

    // stage: coalesced global read, transposed LDS write (one-time conflicts OK)
#pragma unroll
    for (int q = 0; q < 8; q++) {
        int lin = t + q * 256;          // 2048 float4 slots = 64 rows x 32 k4
        int r = lin >> 5, c4 = lin & 31;
        int grow = row0 + r;
        float4 v = make_float4(0.f, 0.f, 0.f, 0.f);
        if (grow < M) v = ((const float4*)(A + (size_t)grow * NF))[c4];
        if (RELU) {
            v.x = fmaxf(v.x, 0.f); v.y = fmaxf(v.y, 0.f);
            v.z = fmaxf(v.z, 0.f); v.w = fmaxf(v.w, 0.f);
        }
        AsT[(c4 * 4 + 0) * 64 + r] = v.x;
        AsT[(c4 * 4 + 1) * 64 + r] = v.y;
        AsT[(c4 * 4 + 2) * 64 + r] = v.z;
        AsT[(c4 * 4 + 3) * 64 + r] = v.w;
    }
    __syncthreads();

    const int tx = t & 15, ty = t >> 4;
    const int c0 = tx * 8, r0 = ty * 4;
    float acc[4][8];
#pragma unroll
    for (int j = 0; j < 4; j++)
#pragma unroll
        for (int c = 0; c < 8; c++) acc[j][c] = 0.f;

#pragma unroll 2
    for (int k = 0; k < NF; k++) {
        float4 a4 = *(const float4*)&AsT[k * 64 + r0];
        const float* wr = W + k * NF + c0;
        float4 w0 = *(const float4*)wr;
        float4 w1 = *(const float4*)(wr + 4);
        float av[4] = {a4.x, a4.y, a4.z, a4.w};
        float wv[8] = {w0.x, w0.y, w0.z, w0.w, w1.x, w1.y, w1.z, w1.w};
#pragma unroll
        for (int j = 0; j < 4; j++)
#pragma unroll
            for (int c = 0; c < 8; c++) acc[j][c] += av[j] * wv[c];
    }

#pragma unroll
    for (int j = 0; j < 4; j++) {
        int grow = row0 + r0 + j;
        if (grow < M) {
            float4 o0 = {acc[j][0], acc[j][1], acc[j][2], acc[j][3]};
            float4 o1 = {acc[j][4], acc[j][5], acc[j][6], acc[j][7]};
            *(float4*)(C + (size_t)grow * NF + c0) = o0;
            *(float4*)(C + (size_t)grow * NF + c0 + 4) = o1;
        }
    }
}

// ---------------- aggregation ----------------
// one block (128 thr) per dst node: 4 edge-groups x 32 lanes x float4.
// 4 row-gathers in flight, dwordx4 accesses, LDS cross-group reduction.

__global__ __launch_bounds__(128) void k_agg(const float* __restrict__ hw,
                                             const float* __restrict__ dinv,
                                             const int* __restrict__ row_ptr,
                                             const int* __restrict__ col,
                                             const float* __restrict__ bias,
                                             float* __restrict__ out) {
    __shared__ float4 red[3][32];
    const int i = blockIdx.x;
    const int lane = threadIdx.x & 31;
    const int grp = threadIdx.x >> 5;
    const float di = dinv[i];
    const int beg = row_ptr[i], end = row_ptr[i + 1];
    const float4* hw4 = (const float4*)hw;

    float4 acc = make_float4(0.f, 0.f, 0.f, 0.f);
    for (int e = beg + grp; e < end; e += 4) {
        int s = col[e];
        float w = dinv[s] * di;
        float4 v = hw4[(size_t)s * 32 + lane];
        acc.x += v.x * w; acc.y += v.y * w; acc.z += v.z * w; acc.w += v.w * w;
    }
    if (grp != 0) {
        red[grp - 1][lane] = acc;
    }
    __syncthreads();
    if (grp == 0) {
        // self-loop term + bias
        float4 v = hw4[(size_t)i * 32 + lane];
        float4 b = ((const float4*)bias)[lane];
        float w = di * di;
        acc.x += v.x * w + b.x; acc.y += v.y * w + b.y;
        acc.z += v.z * w + b.z; acc.w += v.w * w + b.w;
#pragma unroll
        for (int g = 0; g < 3; g++) {
            float4 p = red[g][lane];
            acc.x += p.x; acc.y += p.y; acc.z += p.z; acc.w += p.w;
        }
        ((float4*)out)[(size_t)i * 32 + lane] = acc;
    }
}

// ---------------- node-parallel mean pool (sums; divide in k_mlp) ----------------

#define POOL_CHUNK 64

__global__ __launch_bounds__(128) void k_pool2(const float* __restrict__ h,
                                               const int* __restrict__ batch,
                                               float* __restrict__ pooled) {
    int f = threadIdx.x;
    int n0 = blockIdx.x * POOL_CHUNK;
    int n1 = n0 + POOL_CHUNK;
    if (n1 > N_NODES) n1 = N_NODES;
    if (n0 >= N_NODES) return;
    int g = batch[n0];
    float acc = 0.f;
    for (int n = n0; n < n1; n++) {
        int gn = batch[n];
        if (gn != g) {
            atomicAdd(&pooled[g * NF + f], acc);
            acc = 0.f;
            g = gn;
        }
        acc += fmaxf(h[(size_t)n * NF + f], 0.f);
    }
    atomicAdd(&pooled[g * NF + f], acc);
}

// ---------------- summary MLP ----------------

__global__ void k_mlp(const float* __restrict__ pooled, const int* __restrict__ batch,
                      const float* __restrict__ Ws1, const float* __restrict__ bs1,
                      const float* __restrict__ Ws2, const float* __restrict__ bs2,
                      float* __restrict__ out) {
    __shared__ float row[NF];
    __shared__ float red[NF];
    int g = blockIdx.x, f = threadIdx.x;
    int lo = 0, hi = N_NODES;
    while (lo < hi) { int mid = (lo + hi) >> 1; if (batch[mid] < g) lo = mid + 1; else hi = mid; }
    int start = lo;
    hi = N_NODES;
    while (lo < hi) { int mid = (lo + hi) >> 1; if (batch[mid] < g + 1) lo = mid + 1; else hi = mid; }
    float cnt = (float)(lo - start);
    row[f] = pooled[g * NF + f] / fmaxf(cnt, 1.f);
    __syncthreads();
    float t = bs1[f];
    for (int k = 0; k < NF; k++) t += row[k] * Ws1[k * NF + f];
    t = fmaxf(t, 0.f);
    red[f] = t * Ws2[f];
    __syncthreads();
    for (int s = 64; s > 0; s >>= 1) {
        if (f < s) red[f] += red[f + s];
        __syncthreads();
    }
    if (f == 0) out[g] = red[0] + bs2[0];
}

// ---------------- driver ----------------

extern "C" void kernel_launch(void* const* d_in, const int* in_sizes, int n_in,
                              void* d_out, int out_size, void* d_ws, size_t ws_size,
                              hipStream_t stream) {
    const float* x    = (const float*)d_in[0];
    const int*   ei   = (const int*)d_in[1];
    const int*   batch= (const int*)d_in[2];
    const float* W1 = (const float*)d_in[3];  const float* b1 = (const float*)d_in[4];
    const float* W2 = (const float*)d_in[5];  const float* b2 = (const float*)d_in[6];
    const float* W3 = (const float*)d_in[7];  const float* b3 = (const float*)d_in[8];
    const float* W4 = (const float*)d_in[9];  const float* b4 = (const float*)d_in[10];
    const float* Ws1= (const float*)d_in[11]; const float* bs1= (const float*)d_in[12];
    const float* Ws2= (const float*)d_in[13]; const float* bs2= (const float*)d_in[14];
    float* out = (float*)d_out;

    char* ws = (char*)d_ws;
    size_t off = 0;
    auto alloc = [&](size_t bytes) {
        void* p = ws + off;
        off += (bytes + 255) & ~(size_t)255;
        return p;
    };
    float* bufA   = (float*)alloc((size_t)N_NODES * NF * 4);
    float* bufB   = (float*)alloc((size_t)N_NODES * NF * 4);
    int*   counts = (int*)alloc((size_t)N_NODES * 4);
    int*   row_ptr= (int*)alloc((size_t)(N_NODES + 1) * 4);
    int*   cursor = (int*)alloc((size_t)N_NODES * 4);
    int*   col    = (int*)alloc((size_t)N_EDGES * 4);
    int*   bsums  = (int*)alloc(64 * 4);
    float* dinv   = (float*)alloc((size_t)N_NODES * 4);
    float* pooled = (float*)alloc((size_t)NG * NF * 4);

    hipMemsetAsync(counts, 0, (size_t)N_NODES * 4, stream);
    hipMemsetAsync(pooled, 0, (size_t)NG * NF * 4, stream);
    k_count<<<(N_EDGES + 255) / 256, 256, 0, stream>>>(ei, counts);
    k_dinv<<<(N_NODES + 255) / 256, 256, 0, stream>>>(counts, dinv);
    int nscan = (N_NODES + 2047) / 2048;  // 49
    k_scan1<<<nscan, 256, 0, stream>>>(counts, row_ptr, bsums);
    k_scan2<<<1, 64, 0, stream>>>(bsums, nscan);
    k_scan3<<<(N_NODES + 255) / 256, 256, 0, stream>>>(row_ptr, bsums, cursor);
    k_fill<<<(N_EDGES + 255) / 256, 256, 0, stream>>>(ei, cursor, col);

    int gblocks = (N_NODES + 63) / 64;
    k_gemm<0><<<gblocks, 256, 0, stream>>>(x, W1, bufB, N_NODES);
    k_agg<<<N_NODES, 128, 0, stream>>>(bufB, dinv, row_ptr, col, b1, bufA);
    k_gemm<1><<<gblocks, 256, 0, stream>>>(bufA, W2, bufB, N_NODES);
    k_agg<<<N_NODES, 128, 0, stream>>>(bufB, dinv, row_ptr, col, b2, bufA);
    k_gemm<1><<<gblocks, 256, 0, stream>>>(bufA, W3, bufB, N_NODES);
    k_agg<<<N_NODES, 128, 0, stream>>>(bufB, dinv, row_ptr, col, b3, bufA);
    k_gemm<1><<<gblocks, 256, 0, stream>>>(bufA, W4, bufB, N_NODES);
    k_agg<<<N_NODES, 128, 0, stream>>>(bufB, dinv, row_ptr, col, b4, bufA);

    int pblocks = (N_NODES + POOL_CHUNK - 1) / POOL_CHUNK;
    k_pool2<<<pblocks, 128, 0, stream>>>(bufA, batch, pooled);
    k_mlp<<<NG, 128, 0, stream>>>(pooled, batch, Ws1, bs1, Ws2, bs2, out);
}

// Round 4
// 720.094 us; speedup vs baseline: 1.6852x; 1.0723x over previous
//
#include <hip/hip_runtime.h>

#define N_NODES 100000
#define N_EDGES 600000
#define NF 128
#define NG 256

// ---------------- preprocessing: degrees, dinv, CSR ----------------

__global__ void k_count(const int* __restrict__ ei, int* __restrict__ counts) {
    int e = blockIdx.x * 256 + threadIdx.x;
    if (e < N_EDGES) atomicAdd(&counts[ei[N_EDGES + e]], 1);
}

// scan1 also produces dinv (reads counts anyway)
__global__ void k_scan1(const int* __restrict__ counts, int* __restrict__ row_ptr,
                        int* __restrict__ bsums, float* __restrict__ dinv) {
    __shared__ int s[256];
    int b = blockIdx.x, t = threadIdx.x;
    int base = b * 2048 + t * 8;
    int local[8];
    int sum = 0;
#pragma unroll
    for (int q = 0; q < 8; q++) {
        int idx = base + q;
        int v = (idx < N_NODES) ? counts[idx] : 0;
        if (idx < N_NODES) dinv[idx] = 1.0f / sqrtf((float)(v + 1));
        local[q] = sum;
        sum += v;
    }
    s[t] = sum;
    __syncthreads();
    for (int off = 1; off < 256; off <<= 1) {
        int v = 0;
        if (t >= off) v = s[t - off];
        __syncthreads();
        s[t] += v;
        __syncthreads();
    }
    int excl = s[t] - sum;
#pragma unroll
    for (int q = 0; q < 8; q++) {
        int idx = base + q;
        if (idx < N_NODES) row_ptr[idx] = excl + local[q];
    }
    if (t == 255) bsums[b] = s[255];
}

__global__ void k_scan2(int* bsums, int nb) {
    if (threadIdx.x == 0 && blockIdx.x == 0) {
        int run = 0;
        for (int b = 0; b < nb; b++) { int v = bsums[b]; bsums[b] = run; run += v; }
    }
}

__global__ void k_scan3(int* __restrict__ row_ptr, const int* __restrict__ bsums,
                        int* __restrict__ cursor) {
    int i = blockIdx.x * 256 + threadIdx.x;
    if (i < N_NODES) {
        int v = row_ptr[i] + bsums[i >> 11];
        row_ptr[i] = v;
        cursor[i] = v;
        if (i == 0) row_ptr[N_NODES] = N_EDGES;
    }
}

__global__ void k_fill(const int* __restrict__ ei, int* __restrict__ cursor,
                       int* __restrict__ col) {
    int e = blockIdx.x * 256 + threadIdx.x;
    if (e < N_EDGES) {
        int d = ei[N_EDGES + e];
        int p = atomicAdd(&cursor[d], 1);
        col[p] = ei[e];
    }
}

// ---------------- GEMM: C[M,128] = act(A[M,128]) @ W[128,128] ----------------
// 512 threads, 128-row tile. Thread = 1 row x 32 cols; wave w: rows (w&1)*64+lane,
// cols (w>>1)*32.. (readfirstlane -> wave-uniform W addresses -> scalar loads
// through K$ instead of 1 MB/block of per-lane L1 traffic).
// As stride 129: k-loop read bank = (lane + k) % 32 -> conflict-free.

template <int RELU>
__global__ __launch_bounds__(512) void k_gemm(const float* __restrict__ A,
                                              const float* __restrict__ W,
                                              float* __restrict__ C, int M) {
    __shared__ float As[128 * 129];
    const int t = threadIdx.x;
    const int row0 = blockIdx.x * 128;

    // stage 128 rows, coalesced float4 reads, scalar LDS writes (stride 129)
#pragma unroll
    for (int q = 0; q < 8; q++) {
        int lin = t + q * 512;          // 0..4095 float4 slots = 128 rows x 32
        int r = lin >> 5, c4 = lin & 31;
        int grow = row0 + r;
        float4 v = make_float4(0.f, 0.f, 0.f, 0.f);
        if (grow < M) v = ((const float4*)(A + (size_t)grow * NF))[c4];
        if (RELU) {
            v.x = fmaxf(v.x, 0.f); v.y = fmaxf(v.y, 0.f);
            v.z = fmaxf(v.z, 0.f); v.w = fmaxf(v.w, 0.f);
        }
        float* dst = &As[r * 129 + c4 * 4];
        dst[0] = v.x; dst[1] = v.y; dst[2] = v.z; dst[3] = v.w;
    }
    __syncthreads();

    const int wave = t >> 6;
    const int lane = t & 63;
    const int row = (wave & 1) * 64 + lane;
    const int cq = __builtin_amdgcn_readfirstlane(wave >> 1);  // 0..3, wave-uniform
    const float* wbase = W + cq * 32;

    float acc[32];
#pragma unroll
    for (int c = 0; c < 32; c++) acc[c] = 0.f;

    const float* arow = &As[row * 129];
    for (int k = 0; k < NF; k++) {
        float a = arow[k];
        const float* wr = wbase + k * NF;   // wave-uniform -> s_load
#pragma unroll
        for (int c = 0; c < 32; c++) acc[c] += a * wr[c];
    }

    int grow = row0 + row;
    if (grow < M) {
        float* crow = C + (size_t)grow * NF + cq * 32;
#pragma unroll
        for (int c4 = 0; c4 < 8; c4++) {
            float4 o = {acc[c4 * 4], acc[c4 * 4 + 1], acc[c4 * 4 + 2], acc[c4 * 4 + 3]};
            *(float4*)(crow + c4 * 4) = o;
        }
    }
}

// ---------------- aggregation ----------------
// one WAVE per dst node (4 nodes / 256-thr block). 64 lanes = 32 float4 feature
// lanes x 2 edge slots; shfl_xor(32) reduce; no LDS, no syncthreads.

__global__ __launch_bounds__(256) void k_agg(const float* __restrict__ hw,
                                             const float* __restrict__ dinv,
                                             const int* __restrict__ row_ptr,
                                             const int* __restrict__ col,
                                             const float* __restrict__ bias,
                                             float* __restrict__ out) {
    const int node = blockIdx.x * 4 + (threadIdx.x >> 6);
    const int lane = threadIdx.x & 63;
    const int fl = lane & 31;       // float4 feature slot
    const int half = lane >> 5;     // edge-slot 0/1
    const float4* hw4 = (const float4*)hw;
    const float di = dinv[node];
    const int beg = row_ptr[node], end = row_ptr[node + 1];

    float4 acc = make_float4(0.f, 0.f, 0.f, 0.f);
    for (int e = beg + half; e < end; e += 2) {
        int s = col[e];
        float w = dinv[s] * di;
        float4 v = hw4[(size_t)s * 32 + fl];
        acc.x += v.x * w; acc.y += v.y * w; acc.z += v.z * w; acc.w += v.w * w;
    }
    acc.x += __shfl_xor(acc.x, 32, 64);
    acc.y += __shfl_xor(acc.y, 32, 64);
    acc.z += __shfl_xor(acc.z, 32, 64);
    acc.w += __shfl_xor(acc.w, 32, 64);
    if (half == 0) {
        float4 v = hw4[(size_t)node * 32 + fl];
        float4 b = ((const float4*)bias)[fl];
        float w = di * di;
        acc.x += v.x * w + b.x; acc.y += v.y * w + b.y;
        acc.z += v.z * w + b.z; acc.w += v.w * w + b.w;
        ((float4*)out)[(size_t)node * 32 + fl] = acc;
    }
}

// ---------------- node-parallel mean pool (sums; divide in k_mlp) ----------------

#define POOL_CHUNK 64

__global__ __launch_bounds__(128) void k_pool2(const float* __restrict__ h,
                                               const int* __restrict__ batch,
                                               float* __restrict__ pooled) {
    int f = threadIdx.x;
    int n0 = blockIdx.x * POOL_CHUNK;
    int n1 = n0 + POOL_CHUNK;
    if (n1 > N_NODES) n1 = N_NODES;
    if (n0 >= N_NODES) return;
    int g = batch[n0];
    float acc = 0.f;
    for (int n = n0; n < n1; n++) {
        int gn = batch[n];
        if (gn != g) {
            atomicAdd(&pooled[g * NF + f], acc);
            acc = 0.f;
            g = gn;
        }
        acc += fmaxf(h[(size_t)n * NF + f], 0.f);
    }
    atomicAdd(&pooled[g * NF + f], acc);
}

// ---------------- summary MLP ----------------

__global__ void k_mlp(const float* __restrict__ pooled, const int* __restrict__ batch,
                      const float* __restrict__ Ws1, const float* __restrict__ bs1,
                      const float* __restrict__ Ws2, const float* __restrict__ bs2,
                      float* __restrict__ out) {
    __shared__ float row[NF];
    __shared__ float red[NF];
    int g = blockIdx.x, f = threadIdx.x;
    int lo = 0, hi = N_NODES;
    while (lo < hi) { int mid = (lo + hi) >> 1; if (batch[mid] < g) lo = mid + 1; else hi = mid; }
    int start = lo;
    hi = N_NODES;
    while (lo < hi) { int mid = (lo + hi) >> 1; if (batch[mid] < g + 1) lo = mid + 1; else hi = mid; }
    float cnt = (float)(lo - start);
    row[f] = pooled[g * NF + f] / fmaxf(cnt, 1.f);
    __syncthreads();
    float t = bs1[f];
    for (int k = 0; k < NF; k++) t += row[k] * Ws1[k * NF + f];
    t = fmaxf(t, 0.f);
    red[f] = t * Ws2[f];
    __syncthreads();
    for (int s = 64; s > 0; s >>= 1) {
        if (f < s) red[f] += red[f + s];
        __syncthreads();
    }
    if (f == 0) out[g] = red[0] + bs2[0];
}

// ---------------- driver ----------------

extern "C" void kernel_launch(void* const* d_in, const int* in_sizes, int n_in,
                              void* d_out, int out_size, void* d_ws, size_t ws_size,
                              hipStream_t stream) {
    const float* x    = (const float*)d_in[0];
    const int*   ei   = (const int*)d_in[1];
    const int*   batch= (const int*)d_in[2];
    const float* W1 = (const float*)d_in[3];  const float* b1 = (const float*)d_in[4];
    const float* W2 = (const float*)d_in[5];  const float* b2 = (const float*)d_in[6];
    const float* W3 = (const float*)d_in[7];  const float* b3 = (const float*)d_in[8];
    const float* W4 = (const float*)d_in[9];  const float* b4 = (const float*)d_in[10];
    const float* Ws1= (const float*)d_in[11]; const float* bs1= (const float*)d_in[12];
    const float* Ws2= (const float*)d_in[13]; const float* bs2= (const float*)d_in[14];
    float* out = (float*)d_out;

    char* ws = (char*)d_ws;
    size_t off = 0;
    auto alloc = [&](size_t bytes) {
        void* p = ws + off;
        off += (bytes + 255) & ~(size_t)255;
        return p;
    };
    float* bufA   = (float*)alloc((size_t)N_NODES * NF * 4);
    float* bufB   = (float*)alloc((size_t)N_NODES * NF * 4);
    int*   counts = (int*)alloc((size_t)N_NODES * 4);
    int*   row_ptr= (int*)alloc((size_t)(N_NODES + 1) * 4);
    int*   cursor = (int*)alloc((size_t)N_NODES * 4);
    int*   col    = (int*)alloc((size_t)N_EDGES * 4);
    int*   bsums  = (int*)alloc(64 * 4);
    float* dinv   = (float*)alloc((size_t)N_NODES * 4);
    float* pooled = (float*)alloc((size_t)NG * NF * 4);

    hipMemsetAsync(counts, 0, (size_t)N_NODES * 4, stream);
    hipMemsetAsync(pooled, 0, (size_t)NG * NF * 4, stream);
    k_count<<<(N_EDGES + 255) / 256, 256, 0, stream>>>(ei, counts);
    int nscan = (N_NODES + 2047) / 2048;  // 49
    k_scan1<<<nscan, 256, 0, stream>>>(counts, row_ptr, bsums, dinv);
    k_scan2<<<1, 64, 0, stream>>>(bsums, nscan);
    k_scan3<<<(N_NODES + 255) / 256, 256, 0, stream>>>(row_ptr, bsums, cursor);
    k_fill<<<(N_EDGES + 255) / 256, 256, 0, stream>>>(ei, cursor, col);

    int gblocks = (N_NODES + 127) / 128;   // 782
    int ablocks = N_NODES / 4;             // 25000 (exact)
    k_gemm<0><<<gblocks, 512, 0, stream>>>(x, W1, bufB, N_NODES);
    k_agg<<<ablocks, 256, 0, stream>>>(bufB, dinv, row_ptr, col, b1, bufA);
    k_gemm<1><<<gblocks, 512, 0, stream>>>(bufA, W2, bufB, N_NODES);
    k_agg<<<ablocks, 256, 0, stream>>>(bufB, dinv, row_ptr, col, b2, bufA);
    k_gemm<1><<<gblocks, 512, 0, stream>>>(bufA, W3, bufB, N_NODES);
    k_agg<<<ablocks, 256, 0, stream>>>(bufB, dinv, row_ptr, col, b3, bufA);
    k_gemm<1><<<gblocks, 512, 0, stream>>>(bufA, W4, bufB, N_NODES);
    k_agg<<<ablocks, 256, 0, stream>>>(bufB, dinv, row_ptr, col, b4, bufA);

    int pblocks = (N_NODES + POOL_CHUNK - 1) / POOL_CHUNK;
    k_pool2<<<pblocks, 128, 0, stream>>>(bufA, batch, pooled);
    k_mlp<<<NG, 128, 0, stream>>>(pooled, batch, Ws1, bs1, Ws2, bs2, out);
}

// Round 5
// 568.946 us; speedup vs baseline: 2.1329x; 1.2657x over previous
//
#include <hip/hip_runtime.h>

#define N_NODES 100000
#define N_EDGES 600000
#define NF 128
#define NG 256

typedef _Float16 f16;
typedef f16 half8 __attribute__((ext_vector_type(8)));
typedef f16 half4v __attribute__((ext_vector_type(4)));
typedef float float4v __attribute__((ext_vector_type(4)));

// ---------------- preprocessing: degrees, dinv, CSR ----------------

__global__ void k_count(const int* __restrict__ ei, int* __restrict__ counts) {
    int e = blockIdx.x * 256 + threadIdx.x;
    if (e < N_EDGES) atomicAdd(&counts[ei[N_EDGES + e]], 1);
}

__global__ void k_scan1(const int* __restrict__ counts, int* __restrict__ row_ptr,
                        int* __restrict__ bsums, float* __restrict__ dinv) {
    __shared__ int s[256];
    int b = blockIdx.x, t = threadIdx.x;
    int base = b * 2048 + t * 8;
    int local[8];
    int sum = 0;
#pragma unroll
    for (int q = 0; q < 8; q++) {
        int idx = base + q;
        int v = (idx < N_NODES) ? counts[idx] : 0;
        if (idx < N_NODES) dinv[idx] = 1.0f / sqrtf((float)(v + 1));
        local[q] = sum;
        sum += v;
    }
    s[t] = sum;
    __syncthreads();
    for (int off = 1; off < 256; off <<= 1) {
        int v = 0;
        if (t >= off) v = s[t - off];
        __syncthreads();
        s[t] += v;
        __syncthreads();
    }
    int excl = s[t] - sum;
#pragma unroll
    for (int q = 0; q < 8; q++) {
        int idx = base + q;
        if (idx < N_NODES) row_ptr[idx] = excl + local[q];
    }
    if (t == 255) bsums[b] = s[255];
}

__global__ void k_scan2(int* bsums, int nb) {
    if (threadIdx.x == 0 && blockIdx.x == 0) {
        int run = 0;
        for (int b = 0; b < nb; b++) { int v = bsums[b]; bsums[b] = run; run += v; }
    }
}

__global__ void k_scan3(int* __restrict__ row_ptr, const int* __restrict__ bsums,
                        int* __restrict__ cursor) {
    int i = blockIdx.x * 256 + threadIdx.x;
    if (i < N_NODES) {
        int v = row_ptr[i] + bsums[i >> 11];
        row_ptr[i] = v;
        cursor[i] = v;
        if (i == 0) row_ptr[N_NODES] = N_EDGES;
    }
}

__global__ void k_fill(const int* __restrict__ ei, int* __restrict__ cursor,
                       int* __restrict__ col) {
    int e = blockIdx.x * 256 + threadIdx.x;
    if (e < N_EDGES) {
        int d = ei[N_EDGES + e];
        int p = atomicAdd(&cursor[d], 1);
        col[p] = ei[e];
    }
}

// ---------------- W prep: split fp32 W[k][n] into fp16 hi/lo, TRANSPOSED ----
// WT[n][k] layout so B-fragment lanes read 8 contiguous k (16 B).

__global__ void k_wprep(const float* __restrict__ W1, const float* __restrict__ W2,
                        const float* __restrict__ W3, const float* __restrict__ W4,
                        f16* __restrict__ wtH, f16* __restrict__ wtL) {
    int idx = blockIdx.x * 256 + threadIdx.x;   // 4*16384 total
    int layer = idx >> 14;
    int rem = idx & 16383;
    int n = rem >> 7, k = rem & 127;
    const float* W = (layer == 0) ? W1 : (layer == 1) ? W2 : (layer == 2) ? W3 : W4;
    float w = W[k * NF + n];
    f16 h = (f16)w;
    f16 l = (f16)(w - (float)h);
    wtH[layer * 16384 + n * NF + k] = h;
    wtL[layer * 16384 + n * NF + k] = l;
}

// ---------------- GEMM: C[M,128] = A[M,128] @ W[128,128], fp16-split MFMA ----
// 64-row tile, 256 thr (4 waves). Wave w: cols 32w..32w+31 (2 col-tiles),
// all 4 row-tiles. A staged in LDS as fp16 hi/lo, row stride 136 (bank-even).
// B frags straight from global WT (L1-resident). C transposed via reused LDS.
// XIN=1: A is fp32 x (split in-register). XIN=0: A is fp16 hi/lo planes.

template <int XIN>
__global__ __launch_bounds__(256, 4) void k_gemm_mfma(
    const float* __restrict__ X, const f16* __restrict__ AH, const f16* __restrict__ AL,
    const f16* __restrict__ WTH, const f16* __restrict__ WTL,
    float* __restrict__ C, int M) {
    __shared__ __align__(16) char smem[64 * 136 * 2 * 2];  // 34816 B
    f16* Ah = (f16*)smem;
    f16* Al = Ah + 64 * 136;
    float* Cs = (float*)smem;           // reused after k-loop (33792 B)

    const int t = threadIdx.x;
    const int row0 = blockIdx.x * 64;

    if (XIN) {
        // fp32 input: 2048 float4 slots = 64 rows x 32, split to hi/lo
#pragma unroll
        for (int q = 0; q < 8; q++) {
            int lin = t + q * 256;
            int r = lin >> 5, c4 = lin & 31;
            float4 v = make_float4(0.f, 0.f, 0.f, 0.f);
            if (row0 + r < M) v = ((const float4*)(X + (size_t)(row0 + r) * NF))[c4];
            f16 h0 = (f16)v.x, h1 = (f16)v.y, h2 = (f16)v.z, h3 = (f16)v.w;
            half4v hv = {h0, h1, h2, h3};
            half4v lv = {(f16)(v.x - (float)h0), (f16)(v.y - (float)h1),
                         (f16)(v.z - (float)h2), (f16)(v.w - (float)h3)};
            *(half4v*)&Ah[r * 136 + c4 * 4] = hv;
            *(half4v*)&Al[r * 136 + c4 * 4] = lv;
        }
    } else {
        // fp16 planes: 1024 half8 slots per plane
#pragma unroll
        for (int q = 0; q < 4; q++) {
            int lin = t + q * 256;
            int r = lin >> 4, c8 = lin & 15;
            half8 v = {};
            if (row0 + r < M) v = *(const half8*)(AH + (size_t)(row0 + r) * NF + c8 * 8);
            *(half8*)&Ah[r * 136 + c8 * 8] = v;
        }
#pragma unroll
        for (int q = 0; q < 4; q++) {
            int lin = t + q * 256;
            int r = lin >> 4, c8 = lin & 15;
            half8 v = {};
            if (row0 + r < M) v = *(const half8*)(AL + (size_t)(row0 + r) * NF + c8 * 8);
            *(half8*)&Al[r * 136 + c8 * 8] = v;
        }
    }
    __syncthreads();

    const int wave = t >> 6;
    const int lane = t & 63;
    const int nl = lane & 15;       // m for A-frag / n for B-frag / col for C
    const int quad = lane >> 4;

    float4v acc[2][4];
#pragma unroll
    for (int ct = 0; ct < 2; ct++)
#pragma unroll
        for (int rt = 0; rt < 4; rt++) acc[ct][rt] = (float4v)0.f;

#pragma unroll
    for (int s = 0; s < 4; s++) {
        half8 fah[4], fal[4], fbh[2], fbl[2];
#pragma unroll
        for (int rt = 0; rt < 4; rt++) {
            int eo = (rt * 16 + nl) * 136 + s * 32 + quad * 8;
            fah[rt] = *(half8*)&Ah[eo];
            fal[rt] = *(half8*)&Al[eo];
        }
#pragma unroll
        for (int ct = 0; ct < 2; ct++) {
            int ng = wave * 32 + ct * 16 + nl;
            size_t wo = (size_t)ng * NF + s * 32 + quad * 8;
            fbh[ct] = *(const half8*)(WTH + wo);
            fbl[ct] = *(const half8*)(WTL + wo);
        }
#pragma unroll
        for (int ct = 0; ct < 2; ct++)
#pragma unroll
            for (int rt = 0; rt < 4; rt++) {
                acc[ct][rt] = __builtin_amdgcn_mfma_f32_16x16x32_f16(fah[rt], fbh[ct], acc[ct][rt], 0, 0, 0);
                acc[ct][rt] = __builtin_amdgcn_mfma_f32_16x16x32_f16(fal[rt], fbh[ct], acc[ct][rt], 0, 0, 0);
                acc[ct][rt] = __builtin_amdgcn_mfma_f32_16x16x32_f16(fah[rt], fbl[ct], acc[ct][rt], 0, 0, 0);
            }
    }

    __syncthreads();  // A tiles dead; reuse LDS for C transpose
#pragma unroll
    for (int ct = 0; ct < 2; ct++)
#pragma unroll
        for (int rt = 0; rt < 4; rt++)
#pragma unroll
            for (int r = 0; r < 4; r++) {
                int row = rt * 16 + quad * 4 + r;
                int colx = wave * 32 + ct * 16 + nl;
                Cs[row * 132 + colx] = acc[ct][rt][r];
            }
    __syncthreads();
#pragma unroll
    for (int q = 0; q < 8; q++) {
        int lin = t + q * 256;
        int r = lin >> 5, c4 = lin & 31;
        if (row0 + r < M)
            ((float4*)(C + (size_t)(row0 + r) * NF))[c4] = *(float4*)&Cs[r * 132 + c4 * 4];
    }
}

// ---------------- aggregation ----------------
// one WAVE per dst node (4/block). Epilogue: +bias, relu, split to fp16 hi/lo.

__global__ __launch_bounds__(256) void k_agg(const float* __restrict__ hw,
                                             const float* __restrict__ dinv,
                                             const int* __restrict__ row_ptr,
                                             const int* __restrict__ col,
                                             const float* __restrict__ bias,
                                             f16* __restrict__ outH,
                                             f16* __restrict__ outL) {
    const int node = blockIdx.x * 4 + (threadIdx.x >> 6);
    const int lane = threadIdx.x & 63;
    const int fl = lane & 31;
    const int half = lane >> 5;
    const float4* hw4 = (const float4*)hw;
    const float di = dinv[node];
    const int beg = row_ptr[node], end = row_ptr[node + 1];

    float4 acc = make_float4(0.f, 0.f, 0.f, 0.f);
    for (int e = beg + half; e < end; e += 2) {
        int s = col[e];
        float w = dinv[s] * di;
        float4 v = hw4[(size_t)s * 32 + fl];
        acc.x += v.x * w; acc.y += v.y * w; acc.z += v.z * w; acc.w += v.w * w;
    }
    acc.x += __shfl_xor(acc.x, 32, 64);
    acc.y += __shfl_xor(acc.y, 32, 64);
    acc.z += __shfl_xor(acc.z, 32, 64);
    acc.w += __shfl_xor(acc.w, 32, 64);
    if (half == 0) {
        float4 v = hw4[(size_t)node * 32 + fl];
        float4 b = ((const float4*)bias)[fl];
        float w = di * di;
        acc.x = fmaxf(acc.x + v.x * w + b.x, 0.f);
        acc.y = fmaxf(acc.y + v.y * w + b.y, 0.f);
        acc.z = fmaxf(acc.z + v.z * w + b.z, 0.f);
        acc.w = fmaxf(acc.w + v.w * w + b.w, 0.f);
        f16 h0 = (f16)acc.x, h1 = (f16)acc.y, h2 = (f16)acc.z, h3 = (f16)acc.w;
        half4v hv = {h0, h1, h2, h3};
        half4v lv = {(f16)(acc.x - (float)h0), (f16)(acc.y - (float)h1),
                     (f16)(acc.z - (float)h2), (f16)(acc.w - (float)h3)};
        *(half4v*)(outH + (size_t)node * NF + fl * 4) = hv;
        *(half4v*)(outL + (size_t)node * NF + fl * 4) = lv;
    }
}

// ---------------- node-parallel mean pool (sums; divide in k_mlp) ----------
// h already relu'd by agg; h = hi + lo.

#define POOL_CHUNK 64

__global__ __launch_bounds__(128) void k_pool2(const f16* __restrict__ hH,
                                               const f16* __restrict__ hL,
                                               const int* __restrict__ batch,
                                               float* __restrict__ pooled) {
    int f = threadIdx.x;
    int n0 = blockIdx.x * POOL_CHUNK;
    int n1 = n0 + POOL_CHUNK;
    if (n1 > N_NODES) n1 = N_NODES;
    if (n0 >= N_NODES) return;
    int g = batch[n0];
    float acc = 0.f;
    for (int n = n0; n < n1; n++) {
        int gn = batch[n];
        if (gn != g) {
            atomicAdd(&pooled[g * NF + f], acc);
            acc = 0.f;
            g = gn;
        }
        acc += (float)hH[(size_t)n * NF + f] + (float)hL[(size_t)n * NF + f];
    }
    atomicAdd(&pooled[g * NF + f], acc);
}

// ---------------- summary MLP ----------------

__global__ void k_mlp(const float* __restrict__ pooled, const int* __restrict__ batch,
                      const float* __restrict__ Ws1, const float* __restrict__ bs1,
                      const float* __restrict__ Ws2, const float* __restrict__ bs2,
                      float* __restrict__ out) {
    __shared__ float row[NF];
    __shared__ float red[NF];
    int g = blockIdx.x, f = threadIdx.x;
    int lo = 0, hi = N_NODES;
    while (lo < hi) { int mid = (lo + hi) >> 1; if (batch[mid] < g) lo = mid + 1; else hi = mid; }
    int start = lo;
    hi = N_NODES;
    while (lo < hi) { int mid = (lo + hi) >> 1; if (batch[mid] < g + 1) lo = mid + 1; else hi = mid; }
    float cnt = (float)(lo - start);
    row[f] = pooled[g * NF + f] / fmaxf(cnt, 1.f);
    __syncthreads();
    float t = bs1[f];
    for (int k = 0; k < NF; k++) t += row[k] * Ws1[k * NF + f];
    t = fmaxf(t, 0.f);
    red[f] = t * Ws2[f];
    __syncthreads();
    for (int s = 64; s > 0; s >>= 1) {
        if (f < s) red[f] += red[f + s];
        __syncthreads();
    }
    if (f == 0) out[g] = red[0] + bs2[0];
}

// ---------------- driver ----------------

extern "C" void kernel_launch(void* const* d_in, const int* in_sizes, int n_in,
                              void* d_out, int out_size, void* d_ws, size_t ws_size,
                              hipStream_t stream) {
    const float* x    = (const float*)d_in[0];
    const int*   ei   = (const int*)d_in[1];
    const int*   batch= (const int*)d_in[2];
    const float* W1 = (const float*)d_in[3];  const float* b1 = (const float*)d_in[4];
    const float* W2 = (const float*)d_in[5];  const float* b2 = (const float*)d_in[6];
    const float* W3 = (const float*)d_in[7];  const float* b3 = (const float*)d_in[8];
    const float* W4 = (const float*)d_in[9];  const float* b4 = (const float*)d_in[10];
    const float* Ws1= (const float*)d_in[11]; const float* bs1= (const float*)d_in[12];
    const float* Ws2= (const float*)d_in[13]; const float* bs2= (const float*)d_in[14];
    float* out = (float*)d_out;

    char* ws = (char*)d_ws;
    size_t off = 0;
    auto alloc = [&](size_t bytes) {
        void* p = ws + off;
        off += (bytes + 255) & ~(size_t)255;
        return p;
    };
    float* bufHW  = (float*)alloc((size_t)N_NODES * NF * 4);
    f16*   hHi    = (f16*)alloc((size_t)N_NODES * NF * 2);
    f16*   hLo    = (f16*)alloc((size_t)N_NODES * NF * 2);
    f16*   wtH    = (f16*)alloc((size_t)4 * NF * NF * 2);
    f16*   wtL    = (f16*)alloc((size_t)4 * NF * NF * 2);
    int*   counts = (int*)alloc((size_t)N_NODES * 4);
    int*   row_ptr= (int*)alloc((size_t)(N_NODES + 1) * 4);
    int*   cursor = (int*)alloc((size_t)N_NODES * 4);
    int*   col    = (int*)alloc((size_t)N_EDGES * 4);
    int*   bsums  = (int*)alloc(64 * 4);
    float* dinv   = (float*)alloc((size_t)N_NODES * 4);
    float* pooled = (float*)alloc((size_t)NG * NF * 4);

    hipMemsetAsync(counts, 0, (size_t)N_NODES * 4, stream);
    hipMemsetAsync(pooled, 0, (size_t)NG * NF * 4, stream);
    k_count<<<(N_EDGES + 255) / 256, 256, 0, stream>>>(ei, counts);
    int nscan = (N_NODES + 2047) / 2048;  // 49
    k_scan1<<<nscan, 256, 0, stream>>>(counts, row_ptr, bsums, dinv);
    k_scan2<<<1, 64, 0, stream>>>(bsums, nscan);
    k_scan3<<<(N_NODES + 255) / 256, 256, 0, stream>>>(row_ptr, bsums, cursor);
    k_fill<<<(N_EDGES + 255) / 256, 256, 0, stream>>>(ei, cursor, col);
    k_wprep<<<256, 256, 0, stream>>>(W1, W2, W3, W4, wtH, wtL);

    int gblocks = (N_NODES + 63) / 64;     // 1563
    int ablocks = N_NODES / 4;             // 25000
    k_gemm_mfma<1><<<gblocks, 256, 0, stream>>>(x, nullptr, nullptr, wtH, wtL, bufHW, N_NODES);
    k_agg<<<ablocks, 256, 0, stream>>>(bufHW, dinv, row_ptr, col, b1, hHi, hLo);
    k_gemm_mfma<0><<<gblocks, 256, 0, stream>>>(nullptr, hHi, hLo, wtH + 16384, wtL + 16384, bufHW, N_NODES);
    k_agg<<<ablocks, 256, 0, stream>>>(bufHW, dinv, row_ptr, col, b2, hHi, hLo);
    k_gemm_mfma<0><<<gblocks, 256, 0, stream>>>(nullptr, hHi, hLo, wtH + 32768, wtL + 32768, bufHW, N_NODES);
    k_agg<<<ablocks, 256, 0, stream>>>(bufHW, dinv, row_ptr, col, b3, hHi, hLo);
    k_gemm_mfma<0><<<gblocks, 256, 0, stream>>>(nullptr, hHi, hLo, wtH + 49152, wtL + 49152, bufHW, N_NODES);
    k_agg<<<ablocks, 256, 0, stream>>>(bufHW, dinv, row_ptr, col, b4, hHi, hLo);

    int pblocks = (N_NODES + POOL_CHUNK - 1) / POOL_CHUNK;
    k_pool2<<<pblocks, 128, 0, stream>>>(hHi, hLo, batch, pooled);
    k_mlp<<<NG, 128, 0, stream>>>(pooled, batch, Ws1, bs1, Ws2, bs2, out);
}

// Round 6
// 486.203 us; speedup vs baseline: 2.4959x; 1.1702x over previous
//
#include <hip/hip_runtime.h>

#define N_NODES 100000
#define N_EDGES 600000
#define NF 128
#define NG 256

typedef _Float16 f16;
typedef f16 half8 __attribute__((ext_vector_type(8)));
typedef f16 half4v __attribute__((ext_vector_type(4)));
typedef float float4v __attribute__((ext_vector_type(4)));

// ---------------- preprocessing: degrees, dinv, CSR ----------------

__global__ void k_count(const int* __restrict__ ei, int* __restrict__ counts) {
    int e = blockIdx.x * 256 + threadIdx.x;
    if (e < N_EDGES) atomicAdd(&counts[ei[N_EDGES + e]], 1);
}

__global__ void k_scan1(const int* __restrict__ counts, int* __restrict__ row_ptr,
                        int* __restrict__ bsums, float* __restrict__ dinv) {
    __shared__ int s[256];
    int b = blockIdx.x, t = threadIdx.x;
    int base = b * 2048 + t * 8;
    int local[8];
    int sum = 0;
#pragma unroll
    for (int q = 0; q < 8; q++) {
        int idx = base + q;
        int v = (idx < N_NODES) ? counts[idx] : 0;
        if (idx < N_NODES) dinv[idx] = 1.0f / sqrtf((float)(v + 1));
        local[q] = sum;
        sum += v;
    }
    s[t] = sum;
    __syncthreads();
    for (int off = 1; off < 256; off <<= 1) {
        int v = 0;
        if (t >= off) v = s[t - off];
        __syncthreads();
        s[t] += v;
        __syncthreads();
    }
    int excl = s[t] - sum;
#pragma unroll
    for (int q = 0; q < 8; q++) {
        int idx = base + q;
        if (idx < N_NODES) row_ptr[idx] = excl + local[q];
    }
    if (t == 255) bsums[b] = s[255];
}

__global__ void k_scan2(int* bsums, int nb) {
    if (threadIdx.x == 0 && blockIdx.x == 0) {
        int run = 0;
        for (int b = 0; b < nb; b++) { int v = bsums[b]; bsums[b] = run; run += v; }
    }
}

__global__ void k_scan3(int* __restrict__ row_ptr, const int* __restrict__ bsums,
                        int* __restrict__ cursor) {
    int i = blockIdx.x * 256 + threadIdx.x;
    if (i < N_NODES) {
        int v = row_ptr[i] + bsums[i >> 11];
        row_ptr[i] = v;
        cursor[i] = v;
        if (i == 0) row_ptr[N_NODES] = N_EDGES;
    }
}

__global__ void k_fill(const int* __restrict__ ei, int* __restrict__ cursor,
                       int* __restrict__ col) {
    int e = blockIdx.x * 256 + threadIdx.x;
    if (e < N_EDGES) {
        int d = ei[N_EDGES + e];
        int p = atomicAdd(&cursor[d], 1);
        col[p] = ei[e];
    }
}

// ---------------- W prep: split fp32 W[k][n] into fp16 hi/lo, TRANSPOSED ----

__global__ void k_wprep(const float* __restrict__ W1, const float* __restrict__ W2,
                        const float* __restrict__ W3, const float* __restrict__ W4,
                        f16* __restrict__ wtH, f16* __restrict__ wtL) {
    int idx = blockIdx.x * 256 + threadIdx.x;   // 4*16384 total
    int layer = idx >> 14;
    int rem = idx & 16383;
    int n = rem >> 7, k = rem & 127;
    const float* W = (layer == 0) ? W1 : (layer == 1) ? W2 : (layer == 2) ? W3 : W4;
    float w = W[k * NF + n];
    f16 h = (f16)w;
    f16 l = (f16)(w - (float)h);
    wtH[layer * 16384 + n * NF + k] = h;
    wtL[layer * 16384 + n * NF + k] = l;
}

// ---------------- GEMM: Z[M,128] = A[M,128] @ W[128,128], fp16 MFMA --------
// A fp16 single plane (exact), W = Wh + Wl fp16 split -> 2-term MFMA, fp32 acc.
// 64-row tile, 256 thr. B-frags prefetched to regs BEFORE the barrier (global
// loads overlap A staging; k-loop is pure LDS+MFMA). fp16 epilogue via LDS.
// XIN=1: A is fp32 x, rounded to fp16 in staging.

template <int XIN>
__global__ __launch_bounds__(256) void k_gemm_mfma(
    const float* __restrict__ X, const f16* __restrict__ A,
    const f16* __restrict__ WTH, const f16* __restrict__ WTL,
    f16* __restrict__ Z, int M) {
    __shared__ __align__(16) f16 As[64 * 136];   // 17408 B; reused for C out

    const int t = threadIdx.x;
    const int row0 = blockIdx.x * 64;
    const int wave = t >> 6;
    const int lane = t & 63;
    const int nl = lane & 15;
    const int quad = lane >> 4;

    // B prefetch: 16 half8 = 64 VGPRs; issues before the barrier.
    half8 fbh[4][2], fbl[4][2];
#pragma unroll
    for (int s = 0; s < 4; s++)
#pragma unroll
        for (int ct = 0; ct < 2; ct++) {
            int ng = wave * 32 + ct * 16 + nl;
            size_t wo = (size_t)ng * NF + s * 32 + quad * 8;
            fbh[s][ct] = *(const half8*)(WTH + wo);
            fbl[s][ct] = *(const half8*)(WTL + wo);
        }

    if (XIN) {
#pragma unroll
        for (int q = 0; q < 8; q++) {
            int lin = t + q * 256;          // 2048 float4 slots
            int r = lin >> 5, c4 = lin & 31;
            float4 v = make_float4(0.f, 0.f, 0.f, 0.f);
            if (row0 + r < M) v = ((const float4*)(X + (size_t)(row0 + r) * NF))[c4];
            half4v hv = {(f16)v.x, (f16)v.y, (f16)v.z, (f16)v.w};
            *(half4v*)&As[r * 136 + c4 * 4] = hv;
        }
    } else {
#pragma unroll
        for (int q = 0; q < 4; q++) {
            int lin = t + q * 256;          // 1024 half8 slots
            int r = lin >> 4, c8 = lin & 15;
            half8 v = {};
            if (row0 + r < M) v = *(const half8*)(A + (size_t)(row0 + r) * NF + c8 * 8);
            *(half8*)&As[r * 136 + c8 * 8] = v;
        }
    }
    __syncthreads();

    float4v acc[2][4];
#pragma unroll
    for (int ct = 0; ct < 2; ct++)
#pragma unroll
        for (int rt = 0; rt < 4; rt++) acc[ct][rt] = (float4v)0.f;

#pragma unroll
    for (int s = 0; s < 4; s++) {
        half8 fa[4];
#pragma unroll
        for (int rt = 0; rt < 4; rt++)
            fa[rt] = *(half8*)&As[(rt * 16 + nl) * 136 + s * 32 + quad * 8];
#pragma unroll
        for (int ct = 0; ct < 2; ct++)
#pragma unroll
            for (int rt = 0; rt < 4; rt++) {
                acc[ct][rt] = __builtin_amdgcn_mfma_f32_16x16x32_f16(fa[rt], fbh[s][ct], acc[ct][rt], 0, 0, 0);
                acc[ct][rt] = __builtin_amdgcn_mfma_f32_16x16x32_f16(fa[rt], fbl[s][ct], acc[ct][rt], 0, 0, 0);
            }
    }

    __syncthreads();  // A dead; reuse As as f16 C staging (stride 136)
#pragma unroll
    for (int ct = 0; ct < 2; ct++)
#pragma unroll
        for (int rt = 0; rt < 4; rt++)
#pragma unroll
            for (int r = 0; r < 4; r++)
                As[(rt * 16 + quad * 4 + r) * 136 + wave * 32 + ct * 16 + nl] =
                    (f16)acc[ct][rt][r];
    __syncthreads();
#pragma unroll
    for (int q = 0; q < 4; q++) {
        int lin = t + q * 256;
        int r = lin >> 4, c8 = lin & 15;
        if (row0 + r < M)
            *(half8*)(Z + (size_t)(row0 + r) * NF + c8 * 8) = *(half8*)&As[r * 136 + c8 * 8];
    }
}

// ---------------- aggregation: h = relu(b + D^-1/2 (A+I) D^-1/2 z) ---------
// one WAVE per node (4/block): 4 edge-slots x 16 lanes x half8 (256 B rows).
// Self-loop = virtual edge 0. fp32 accumulate, fp16 output.

__global__ __launch_bounds__(256) void k_agg(const f16* __restrict__ z,
                                             const float* __restrict__ dinv,
                                             const int* __restrict__ row_ptr,
                                             const int* __restrict__ col,
                                             const float* __restrict__ bias,
                                             f16* __restrict__ h) {
    const int node = blockIdx.x * 4 + (threadIdx.x >> 6);
    const int lane = threadIdx.x & 63;
    const int fl = lane & 15;       // half8 slot within row
    const int slot = lane >> 4;     // edge slot 0..3
    const half8* z8 = (const half8*)z;
    const float di = dinv[node];
    const int beg = row_ptr[node];
    const int total = row_ptr[node + 1] - beg + 1;  // +1 self

    float acc[8];
#pragma unroll
    for (int j = 0; j < 8; j++) acc[j] = 0.f;

    for (int idx = slot; idx < total; idx += 4) {
        int s; float w;
        if (idx == 0) { s = node; w = di * di; }
        else { s = col[beg + idx - 1]; w = dinv[s] * di; }
        half8 v = z8[(size_t)s * 16 + fl];
#pragma unroll
        for (int j = 0; j < 8; j++) acc[j] += (float)v[j] * w;
    }
#pragma unroll
    for (int j = 0; j < 8; j++) {
        acc[j] += __shfl_xor(acc[j], 16, 64);
        acc[j] += __shfl_xor(acc[j], 32, 64);
    }
    if (slot == 0) {
        float4 b0 = ((const float4*)bias)[fl * 2];
        float4 b1 = ((const float4*)bias)[fl * 2 + 1];
        float bb[8] = {b0.x, b0.y, b0.z, b0.w, b1.x, b1.y, b1.z, b1.w};
        half8 o;
#pragma unroll
        for (int j = 0; j < 8; j++) o[j] = (f16)fmaxf(acc[j] + bb[j], 0.f);
        ((half8*)h)[(size_t)node * 16 + fl] = o;
    }
}

// ---------------- node-parallel mean pool (sums; divide in k_mlp) ----------

#define POOL_CHUNK 64

__global__ __launch_bounds__(128) void k_pool2(const f16* __restrict__ h,
                                               const int* __restrict__ batch,
                                               float* __restrict__ pooled) {
    int f = threadIdx.x;
    int n0 = blockIdx.x * POOL_CHUNK;
    int n1 = n0 + POOL_CHUNK;
    if (n1 > N_NODES) n1 = N_NODES;
    if (n0 >= N_NODES) return;
    int g = batch[n0];
    float acc = 0.f;
    for (int n = n0; n < n1; n++) {
        int gn = batch[n];
        if (gn != g) {
            atomicAdd(&pooled[g * NF + f], acc);
            acc = 0.f;
            g = gn;
        }
        acc += (float)h[(size_t)n * NF + f];   // h already relu'd
    }
    atomicAdd(&pooled[g * NF + f], acc);
}

// ---------------- summary MLP ----------------

__global__ void k_mlp(const float* __restrict__ pooled, const int* __restrict__ batch,
                      const float* __restrict__ Ws1, const float* __restrict__ bs1,
                      const float* __restrict__ Ws2, const float* __restrict__ bs2,
                      float* __restrict__ out) {
    __shared__ float row[NF];
    __shared__ float red[NF];
    int g = blockIdx.x, f = threadIdx.x;
    int lo = 0, hi = N_NODES;
    while (lo < hi) { int mid = (lo + hi) >> 1; if (batch[mid] < g) lo = mid + 1; else hi = mid; }
    int start = lo;
    hi = N_NODES;
    while (lo < hi) { int mid = (lo + hi) >> 1; if (batch[mid] < g + 1) lo = mid + 1; else hi = mid; }
    float cnt = (float)(lo - start);
    row[f] = pooled[g * NF + f] / fmaxf(cnt, 1.f);
    __syncthreads();
    float t = bs1[f];
    for (int k = 0; k < NF; k++) t += row[k] * Ws1[k * NF + f];
    t = fmaxf(t, 0.f);
    red[f] = t * Ws2[f];
    __syncthreads();
    for (int s = 64; s > 0; s >>= 1) {
        if (f < s) red[f] += red[f + s];
        __syncthreads();
    }
    if (f == 0) out[g] = red[0] + bs2[0];
}

// ---------------- driver ----------------

extern "C" void kernel_launch(void* const* d_in, const int* in_sizes, int n_in,
                              void* d_out, int out_size, void* d_ws, size_t ws_size,
                              hipStream_t stream) {
    const float* x    = (const float*)d_in[0];
    const int*   ei   = (const int*)d_in[1];
    const int*   batch= (const int*)d_in[2];
    const float* W1 = (const float*)d_in[3];  const float* b1 = (const float*)d_in[4];
    const float* W2 = (const float*)d_in[5];  const float* b2 = (const float*)d_in[6];
    const float* W3 = (const float*)d_in[7];  const float* b3 = (const float*)d_in[8];
    const float* W4 = (const float*)d_in[9];  const float* b4 = (const float*)d_in[10];
    const float* Ws1= (const float*)d_in[11]; const float* bs1= (const float*)d_in[12];
    const float* Ws2= (const float*)d_in[13]; const float* bs2= (const float*)d_in[14];
    float* out = (float*)d_out;

    char* ws = (char*)d_ws;
    size_t off = 0;
    auto alloc = [&](size_t bytes) {
        void* p = ws + off;
        off += (bytes + 255) & ~(size_t)255;
        return p;
    };
    f16*   bufZ   = (f16*)alloc((size_t)N_NODES * NF * 2);
    f16*   bufH   = (f16*)alloc((size_t)N_NODES * NF * 2);
    f16*   wtH    = (f16*)alloc((size_t)4 * NF * NF * 2);
    f16*   wtL    = (f16*)alloc((size_t)4 * NF * NF * 2);
    int*   counts = (int*)alloc((size_t)N_NODES * 4);
    int*   row_ptr= (int*)alloc((size_t)(N_NODES + 1) * 4);
    int*   cursor = (int*)alloc((size_t)N_NODES * 4);
    int*   col    = (int*)alloc((size_t)N_EDGES * 4);
    int*   bsums  = (int*)alloc(64 * 4);
    float* dinv   = (float*)alloc((size_t)N_NODES * 4);
    float* pooled = (float*)alloc((size_t)NG * NF * 4);

    hipMemsetAsync(counts, 0, (size_t)N_NODES * 4, stream);
    hipMemsetAsync(pooled, 0, (size_t)NG * NF * 4, stream);
    k_count<<<(N_EDGES + 255) / 256, 256, 0, stream>>>(ei, counts);
    int nscan = (N_NODES + 2047) / 2048;  // 49
    k_scan1<<<nscan, 256, 0, stream>>>(counts, row_ptr, bsums, dinv);
    k_scan2<<<1, 64, 0, stream>>>(bsums, nscan);
    k_scan3<<<(N_NODES + 255) / 256, 256, 0, stream>>>(row_ptr, bsums, cursor);
    k_fill<<<(N_EDGES + 255) / 256, 256, 0, stream>>>(ei, cursor, col);
    k_wprep<<<256, 256, 0, stream>>>(W1, W2, W3, W4, wtH, wtL);

    int gblocks = (N_NODES + 63) / 64;     // 1563
    int ablocks = N_NODES / 4;             // 25000
    k_gemm_mfma<1><<<gblocks, 256, 0, stream>>>(x, nullptr, wtH, wtL, bufZ, N_NODES);
    k_agg<<<ablocks, 256, 0, stream>>>(bufZ, dinv, row_ptr, col, b1, bufH);
    k_gemm_mfma<0><<<gblocks, 256, 0, stream>>>(nullptr, bufH, wtH + 16384, wtL + 16384, bufZ, N_NODES);
    k_agg<<<ablocks, 256, 0, stream>>>(bufZ, dinv, row_ptr, col, b2, bufH);
    k_gemm_mfma<0><<<gblocks, 256, 0, stream>>>(nullptr, bufH, wtH + 32768, wtL + 32768, bufZ, N_NODES);
    k_agg<<<ablocks, 256, 0, stream>>>(bufZ, dinv, row_ptr, col, b3, bufH);
    k_gemm_mfma<0><<<gblocks, 256, 0, stream>>>(nullptr, bufH, wtH + 49152, wtL + 49152, bufZ, N_NODES);
    k_agg<<<ablocks, 256, 0, stream>>>(bufZ, dinv, row_ptr, col, b4, bufH);

    int pblocks = (N_NODES + POOL_CHUNK - 1) / POOL_CHUNK;
    k_pool2<<<pblocks, 128, 0, stream>>>(bufH, batch, pooled);
    k_mlp<<<NG, 128, 0, stream>>>(pooled, batch, Ws1, bs1, Ws2, bs2, out);
}

// Round 7
// 427.900 us; speedup vs baseline: 2.8359x; 1.1363x over previous
//
#include <hip/hip_runtime.h>

#define N_NODES 100000
#define N_EDGES 600000
#define NF 128
#define NG 256

typedef _Float16 f16;
typedef f16 half8 __attribute__((ext_vector_type(8)));
typedef f16 half4v __attribute__((ext_vector_type(4)));
typedef float float4v __attribute__((ext_vector_type(4)));

// ---------------- preprocessing: degrees, dinv, CSR ----------------

__global__ void k_count(const int* __restrict__ ei, int* __restrict__ counts) {
    int e = blockIdx.x * 256 + threadIdx.x;
    if (e < N_EDGES) atomicAdd(&counts[ei[N_EDGES + e]], 1);
}

__global__ void k_scan1(const int* __restrict__ counts, int* __restrict__ row_ptr,
                        int* __restrict__ bsums, float* __restrict__ dinv) {
    __shared__ int s[256];
    int b = blockIdx.x, t = threadIdx.x;
    int base = b * 2048 + t * 8;
    int local[8];
    int sum = 0;
#pragma unroll
    for (int q = 0; q < 8; q++) {
        int idx = base + q;
        int v = (idx < N_NODES) ? counts[idx] : 0;
        if (idx < N_NODES) dinv[idx] = 1.0f / sqrtf((float)(v + 1));
        local[q] = sum;
        sum += v;
    }
    s[t] = sum;
    __syncthreads();
    for (int off = 1; off < 256; off <<= 1) {
        int v = 0;
        if (t >= off) v = s[t - off];
        __syncthreads();
        s[t] += v;
        __syncthreads();
    }
    int excl = s[t] - sum;
#pragma unroll
    for (int q = 0; q < 8; q++) {
        int idx = base + q;
        if (idx < N_NODES) row_ptr[idx] = excl + local[q];
    }
    if (t == 255) bsums[b] = s[255];
}

__global__ void k_scan2(int* bsums, int nb) {
    if (threadIdx.x == 0 && blockIdx.x == 0) {
        int run = 0;
        for (int b = 0; b < nb; b++) { int v = bsums[b]; bsums[b] = run; run += v; }
    }
}

__global__ void k_scan3(int* __restrict__ row_ptr, const int* __restrict__ bsums,
                        int* __restrict__ cursor) {
    int i = blockIdx.x * 256 + threadIdx.x;
    if (i < N_NODES) {
        int v = row_ptr[i] + bsums[i >> 11];
        row_ptr[i] = v;
        cursor[i] = v;
        if (i == 0) row_ptr[N_NODES] = N_EDGES;
    }
}

__global__ void k_fill(const int* __restrict__ ei, int* __restrict__ cursor,
                       int* __restrict__ col) {
    int e = blockIdx.x * 256 + threadIdx.x;
    if (e < N_EDGES) {
        int d = ei[N_EDGES + e];
        int p = atomicAdd(&cursor[d], 1);
        col[p] = ei[e];
    }
}

// ---------------- W prep: split fp32 W[k][n] into fp16 hi/lo, TRANSPOSED ----

__global__ void k_wprep(const float* __restrict__ W1, const float* __restrict__ W2,
                        const float* __restrict__ W3, const float* __restrict__ W4,
                        f16* __restrict__ wtH, f16* __restrict__ wtL) {
    int idx = blockIdx.x * 256 + threadIdx.x;   // 4*16384 total
    int layer = idx >> 14;
    int rem = idx & 16383;
    int n = rem >> 7, k = rem & 127;
    const float* W = (layer == 0) ? W1 : (layer == 1) ? W2 : (layer == 2) ? W3 : W4;
    float w = W[k * NF + n];
    f16 h = (f16)w;
    f16 l = (f16)(w - (float)h);
    wtH[layer * 16384 + n * NF + k] = h;
    wtL[layer * 16384 + n * NF + k] = l;
}

// ---------------- GEMM: Z[M,128] = A[M,128] @ W[128,128], fp16 MFMA --------
// (unchanged from R6 — waiting for counters before touching)

template <int XIN>
__global__ __launch_bounds__(256) void k_gemm_mfma(
    const float* __restrict__ X, const f16* __restrict__ A,
    const f16* __restrict__ WTH, const f16* __restrict__ WTL,
    f16* __restrict__ Z, int M) {
    __shared__ __align__(16) f16 As[64 * 136];   // 17408 B; reused for C out

    const int t = threadIdx.x;
    const int row0 = blockIdx.x * 64;
    const int wave = t >> 6;
    const int lane = t & 63;
    const int nl = lane & 15;
    const int quad = lane >> 4;

    half8 fbh[4][2], fbl[4][2];
#pragma unroll
    for (int s = 0; s < 4; s++)
#pragma unroll
        for (int ct = 0; ct < 2; ct++) {
            int ng = wave * 32 + ct * 16 + nl;
            size_t wo = (size_t)ng * NF + s * 32 + quad * 8;
            fbh[s][ct] = *(const half8*)(WTH + wo);
            fbl[s][ct] = *(const half8*)(WTL + wo);
        }

    if (XIN) {
#pragma unroll
        for (int q = 0; q < 8; q++) {
            int lin = t + q * 256;
            int r = lin >> 5, c4 = lin & 31;
            float4 v = make_float4(0.f, 0.f, 0.f, 0.f);
            if (row0 + r < M) v = ((const float4*)(X + (size_t)(row0 + r) * NF))[c4];
            half4v hv = {(f16)v.x, (f16)v.y, (f16)v.z, (f16)v.w};
            *(half4v*)&As[r * 136 + c4 * 4] = hv;
        }
    } else {
#pragma unroll
        for (int q = 0; q < 4; q++) {
            int lin = t + q * 256;
            int r = lin >> 4, c8 = lin & 15;
            half8 v = {};
            if (row0 + r < M) v = *(const half8*)(A + (size_t)(row0 + r) * NF + c8 * 8);
            *(half8*)&As[r * 136 + c8 * 8] = v;
        }
    }
    __syncthreads();

    float4v acc[2][4];
#pragma unroll
    for (int ct = 0; ct < 2; ct++)
#pragma unroll
        for (int rt = 0; rt < 4; rt++) acc[ct][rt] = (float4v)0.f;

#pragma unroll
    for (int s = 0; s < 4; s++) {
        half8 fa[4];
#pragma unroll
        for (int rt = 0; rt < 4; rt++)
            fa[rt] = *(half8*)&As[(rt * 16 + nl) * 136 + s * 32 + quad * 8];
#pragma unroll
        for (int ct = 0; ct < 2; ct++)
#pragma unroll
            for (int rt = 0; rt < 4; rt++) {
                acc[ct][rt] = __builtin_amdgcn_mfma_f32_16x16x32_f16(fa[rt], fbh[s][ct], acc[ct][rt], 0, 0, 0);
                acc[ct][rt] = __builtin_amdgcn_mfma_f32_16x16x32_f16(fa[rt], fbl[s][ct], acc[ct][rt], 0, 0, 0);
            }
    }

    __syncthreads();
#pragma unroll
    for (int ct = 0; ct < 2; ct++)
#pragma unroll
        for (int rt = 0; rt < 4; rt++)
#pragma unroll
            for (int r = 0; r < 4; r++)
                As[(rt * 16 + quad * 4 + r) * 136 + wave * 32 + ct * 16 + nl] =
                    (f16)acc[ct][rt][r];
    __syncthreads();
#pragma unroll
    for (int q = 0; q < 4; q++) {
        int lin = t + q * 256;
        int r = lin >> 4, c8 = lin & 15;
        if (row0 + r < M)
            *(half8*)(Z + (size_t)(row0 + r) * NF + c8 * 8) = *(half8*)&As[r * 136 + c8 * 8];
    }
}

// ---------------- aggregation: h = relu(b + D^-1/2 (A+I) D^-1/2 z) ---------
// 16-lane SLOT per node-run: 256 thr = 16 slots, each slot serially does
// ACHUNK consecutive nodes. Per node: col+dinv for <=16 edges prefetched with
// 2 loads, shfl-broadcast per edge, 2-way unrolled row gathers. No reduce.

#define ACHUNK 4

__global__ __launch_bounds__(256) void k_agg(const f16* __restrict__ z,
                                             const float* __restrict__ dinv,
                                             const int* __restrict__ row_ptr,
                                             const int* __restrict__ col,
                                             const float* __restrict__ bias,
                                             f16* __restrict__ h) {
    const int t = threadIdx.x;
    const int slot = t >> 4;            // 0..15 in block
    const int fl = t & 15;              // half8 chunk within row
    const int sbase = (t & 48);         // slot base lane within wave (slot%4)*16
    const int n0 = (blockIdx.x * 16 + slot) * ACHUNK;
    const half8* z8 = (const half8*)z;

    // bias -> registers, once
    float bb[8];
    {
        float4 b0 = ((const float4*)bias)[fl * 2];
        float4 b1 = ((const float4*)bias)[fl * 2 + 1];
        bb[0] = b0.x; bb[1] = b0.y; bb[2] = b0.z; bb[3] = b0.w;
        bb[4] = b1.x; bb[5] = b1.y; bb[6] = b1.z; bb[7] = b1.w;
    }

    for (int n = n0; n < n0 + ACHUNK && n < N_NODES; n++) {
        const float di = dinv[n];
        const int beg = row_ptr[n];
        const int end = row_ptr[n + 1];

        float acc[8];
        {   // self-loop + bias
            half8 v = z8[(size_t)n * 16 + fl];
            float w = di * di;
#pragma unroll
            for (int j = 0; j < 8; j++) acc[j] = bb[j] + (float)v[j] * w;
        }

        for (int c = beg; c < end; c += 16) {
            int mcnt = end - c; if (mcnt > 16) mcnt = 16;
            // prefetch up to 16 cols + their dinv (2 loads, kills per-edge chain)
            int ce = c + fl;
            int colv = (ce < end) ? col[ce] : 0;
            float dv = dinv[colv];

            int j = 0;
            for (; j + 1 < mcnt; j += 2) {
                int s1 = __shfl(colv, sbase + j, 64);
                float w1 = __shfl(dv, sbase + j, 64) * di;
                int s2 = __shfl(colv, sbase + j + 1, 64);
                float w2 = __shfl(dv, sbase + j + 1, 64) * di;
                half8 v1 = z8[(size_t)s1 * 16 + fl];
                half8 v2 = z8[(size_t)s2 * 16 + fl];
#pragma unroll
                for (int q = 0; q < 8; q++) acc[q] += (float)v1[q] * w1;
#pragma unroll
                for (int q = 0; q < 8; q++) acc[q] += (float)v2[q] * w2;
            }
            if (j < mcnt) {
                int s1 = __shfl(colv, sbase + j, 64);
                float w1 = __shfl(dv, sbase + j, 64) * di;
                half8 v1 = z8[(size_t)s1 * 16 + fl];
#pragma unroll
                for (int q = 0; q < 8; q++) acc[q] += (float)v1[q] * w1;
            }
        }

        half8 o;
#pragma unroll
        for (int j = 0; j < 8; j++) o[j] = (f16)fmaxf(acc[j], 0.f);
        ((half8*)h)[(size_t)n * 16 + fl] = o;
    }
}

// ---------------- node-parallel mean pool (sums; divide in k_mlp) ----------

#define POOL_CHUNK 64

__global__ __launch_bounds__(128) void k_pool2(const f16* __restrict__ h,
                                               const int* __restrict__ batch,
                                               float* __restrict__ pooled) {
    int f = threadIdx.x;
    int n0 = blockIdx.x * POOL_CHUNK;
    int n1 = n0 + POOL_CHUNK;
    if (n1 > N_NODES) n1 = N_NODES;
    if (n0 >= N_NODES) return;
    int g = batch[n0];
    float acc = 0.f;
    for (int n = n0; n < n1; n++) {
        int gn = batch[n];
        if (gn != g) {
            atomicAdd(&pooled[g * NF + f], acc);
            acc = 0.f;
            g = gn;
        }
        acc += (float)h[(size_t)n * NF + f];   // h already relu'd
    }
    atomicAdd(&pooled[g * NF + f], acc);
}

// ---------------- summary MLP ----------------

__global__ void k_mlp(const float* __restrict__ pooled, const int* __restrict__ batch,
                      const float* __restrict__ Ws1, const float* __restrict__ bs1,
                      const float* __restrict__ Ws2, const float* __restrict__ bs2,
                      float* __restrict__ out) {
    __shared__ float row[NF];
    __shared__ float red[NF];
    int g = blockIdx.x, f = threadIdx.x;
    int lo = 0, hi = N_NODES;
    while (lo < hi) { int mid = (lo + hi) >> 1; if (batch[mid] < g) lo = mid + 1; else hi = mid; }
    int start = lo;
    hi = N_NODES;
    while (lo < hi) { int mid = (lo + hi) >> 1; if (batch[mid] < g + 1) lo = mid + 1; else hi = mid; }
    float cnt = (float)(lo - start);
    row[f] = pooled[g * NF + f] / fmaxf(cnt, 1.f);
    __syncthreads();
    float t = bs1[f];
    for (int k = 0; k < NF; k++) t += row[k] * Ws1[k * NF + f];
    t = fmaxf(t, 0.f);
    red[f] = t * Ws2[f];
    __syncthreads();
    for (int s = 64; s > 0; s >>= 1) {
        if (f < s) red[f] += red[f + s];
        __syncthreads();
    }
    if (f == 0) out[g] = red[0] + bs2[0];
}

// ---------------- driver ----------------

extern "C" void kernel_launch(void* const* d_in, const int* in_sizes, int n_in,
                              void* d_out, int out_size, void* d_ws, size_t ws_size,
                              hipStream_t stream) {
    const float* x    = (const float*)d_in[0];
    const int*   ei   = (const int*)d_in[1];
    const int*   batch= (const int*)d_in[2];
    const float* W1 = (const float*)d_in[3];  const float* b1 = (const float*)d_in[4];
    const float* W2 = (const float*)d_in[5];  const float* b2 = (const float*)d_in[6];
    const float* W3 = (const float*)d_in[7];  const float* b3 = (const float*)d_in[8];
    const float* W4 = (const float*)d_in[9];  const float* b4 = (const float*)d_in[10];
    const float* Ws1= (const float*)d_in[11]; const float* bs1= (const float*)d_in[12];
    const float* Ws2= (const float*)d_in[13]; const float* bs2= (const float*)d_in[14];
    float* out = (float*)d_out;

    char* ws = (char*)d_ws;
    size_t off = 0;
    auto alloc = [&](size_t bytes) {
        void* p = ws + off;
        off += (bytes + 255) & ~(size_t)255;
        return p;
    };
    f16*   bufZ   = (f16*)alloc((size_t)N_NODES * NF * 2);
    f16*   bufH   = (f16*)alloc((size_t)N_NODES * NF * 2);
    f16*   wtH    = (f16*)alloc((size_t)4 * NF * NF * 2);
    f16*   wtL    = (f16*)alloc((size_t)4 * NF * NF * 2);
    int*   counts = (int*)alloc((size_t)N_NODES * 4);
    int*   row_ptr= (int*)alloc((size_t)(N_NODES + 1) * 4);
    int*   cursor = (int*)alloc((size_t)N_NODES * 4);
    int*   col    = (int*)alloc((size_t)N_EDGES * 4);
    int*   bsums  = (int*)alloc(64 * 4);
    float* dinv   = (float*)alloc((size_t)N_NODES * 4);
    float* pooled = (float*)alloc((size_t)NG * NF * 4);

    hipMemsetAsync(counts, 0, (size_t)N_NODES * 4, stream);
    hipMemsetAsync(pooled, 0, (size_t)NG * NF * 4, stream);
    k_count<<<(N_EDGES + 255) / 256, 256, 0, stream>>>(ei, counts);
    int nscan = (N_NODES + 2047) / 2048;  // 49
    k_scan1<<<nscan, 256, 0, stream>>>(counts, row_ptr, bsums, dinv);
    k_scan2<<<1, 64, 0, stream>>>(bsums, nscan);
    k_scan3<<<(N_NODES + 255) / 256, 256, 0, stream>>>(row_ptr, bsums, cursor);
    k_fill<<<(N_EDGES + 255) / 256, 256, 0, stream>>>(ei, cursor, col);
    k_wprep<<<256, 256, 0, stream>>>(W1, W2, W3, W4, wtH, wtL);

    int gblocks = (N_NODES + 63) / 64;             // 1563
    int ablocks = (N_NODES + 16 * ACHUNK - 1) / (16 * ACHUNK);  // 1563
    k_gemm_mfma<1><<<gblocks, 256, 0, stream>>>(x, nullptr, wtH, wtL, bufZ, N_NODES);
    k_agg<<<ablocks, 256, 0, stream>>>(bufZ, dinv, row_ptr, col, b1, bufH);
    k_gemm_mfma<0><<<gblocks, 256, 0, stream>>>(nullptr, bufH, wtH + 16384, wtL + 16384, bufZ, N_NODES);
    k_agg<<<ablocks, 256, 0, stream>>>(bufZ, dinv, row_ptr, col, b2, bufH);
    k_gemm_mfma<0><<<gblocks, 256, 0, stream>>>(nullptr, bufH, wtH + 32768, wtL + 32768, bufZ, N_NODES);
    k_agg<<<ablocks, 256, 0, stream>>>(bufZ, dinv, row_ptr, col, b3, bufH);
    k_gemm_mfma<0><<<gblocks, 256, 0, stream>>>(nullptr, bufH, wtH + 49152, wtL + 49152, bufZ, N_NODES);
    k_agg<<<ablocks, 256, 0, stream>>>(bufZ, dinv, row_ptr, col, b4, bufH);

    int pblocks = (N_NODES + POOL_CHUNK - 1) / POOL_CHUNK;
    k_pool2<<<pblocks, 128, 0, stream>>>(bufH, batch, pooled);
    k_mlp<<<NG, 128, 0, stream>>>(pooled, batch, Ws1, bs1, Ws2, bs2, out);
}